// Round 17
// baseline (376.915 us; speedup 1.0000x reference)
//
#include <hip/hip_runtime.h>
#include <math.h>

#define HW 4096
#define EPSV 1e-5f

typedef _Float16 half8 __attribute__((ext_vector_type(8)));
typedef float f32x4 __attribute__((ext_vector_type(4)));
union H8 { half8 v; ushort4 q[2]; uint4 u4; };

// slab layout (float offsets) — lifetime-aliased, 15,204,352 floats/slab
#define SLAB_F  15204352ull
#define OFF_Y1A 0
#define OFF_Y1B 2097152
#define OFF_Y2A 6291456
#define OFF_Y2B 8388608
#define OFF_CCB 12582912
#define OFF_P2  14680064
#define OFF_P1  6291456

// ---------------- bn stats over x: one (b,c) plane per block, float4 ----------------
__global__ __launch_bounds__(256) void bn_partial_kernel(
    const float* __restrict__ x, float* __restrict__ pstat) {
  int c = blockIdx.x, b = blockIdx.y;
  int tid = threadIdx.x;
  const float4* p = (const float4*)(x + ((size_t)b * 64 + c) * HW);
  float sm = 0.f, s2 = 0.f;
  #pragma unroll
  for (int i = 0; i < 4; i++) {
    float4 v = p[tid + i * 256];
    sm += v.x + v.y + v.z + v.w;
    s2 += v.x * v.x + v.y * v.y + v.z * v.z + v.w * v.w;
  }
  __shared__ float sh[2][256];
  sh[0][tid] = sm; sh[1][tid] = s2;
  __syncthreads();
  for (int off = 128; off > 0; off >>= 1) {
    if (tid < off) { sh[0][tid] += sh[0][tid + off]; sh[1][tid] += sh[1][tid + off]; }
    __syncthreads();
  }
  if (tid == 0) {
    pstat[((size_t)b * 64 + c) * 2] = sh[0][0];
    pstat[((size_t)b * 64 + c) * 2 + 1] = sh[1][0];
  }
}

// ---------------- bn stats over v (f16): one (br,b,c) plane per block ----------------
__global__ __launch_bounds__(256) void bnv_partial_kernel(
    const _Float16* __restrict__ vb0, size_t vstrideH, float* __restrict__ pstat) {
  int c = blockIdx.x, b = blockIdx.y, br = blockIdx.z;
  int tid = threadIdx.x;
  const _Float16* row = vb0 + (size_t)br * vstrideH + ((size_t)b * 64 + c) * HW;
  float sm = 0.f, s2 = 0.f;
  #pragma unroll
  for (int i = 0; i < 2; i++) {
    H8 v; v.u4 = *(const uint4*)(row + (tid + i * 256) * 8);
    #pragma unroll
    for (int k = 0; k < 8; k++) { float t = (float)v.v[k]; sm += t; s2 += t * t; }
  }
  __shared__ float sh[2][256];
  sh[0][tid] = sm; sh[1][tid] = s2;
  __syncthreads();
  for (int off = 128; off > 0; off >>= 1) {
    if (tid < off) { sh[0][tid] += sh[0][tid + off]; sh[1][tid] += sh[1][tid + off]; }
    __syncthreads();
  }
  if (tid == 0) {
    pstat[(((size_t)br * 32 + b) * 64 + c) * 2] = sh[0][0];
    pstat[(((size_t)br * 32 + b) * 64 + c) * 2 + 1] = sh[1][0];
  }
}

// ---------------- pack static conv weights into MFMA A-fragment order ----------------
__global__ __launch_bounds__(256) void pack_static_kernel(
    const float* __restrict__ wk1c1, const float* __restrict__ wk1c2,
    const float* __restrict__ wk2c1, const float* __restrict__ wk2c2,
    const float* __restrict__ wconv, _Float16* __restrict__ wpk) {
  int idx = blockIdx.x * 256 + threadIdx.x;  // 258048
  int j = idx & 7, lane = (idx >> 3) & 63;
  int tap = (idx >> 9) % 9;
  int chunk = (idx / 4608) % 14;
  int br = idx / 64512;
  int g = lane >> 4;
  int c = (j < 4) ? 4 * g + j : 16 + 4 * g + (j - 4);
  const float* src; int ol0;
  if (chunk < 2)       { src = wk1c1 + (size_t)br * 32 * 288; ol0 = chunk * 16; }
  else if (chunk < 6)  { src = wk1c2 + (size_t)br * 64 * 288; ol0 = (chunk - 2) * 16; }
  else if (chunk < 8)  { src = wk2c1 + (size_t)br * 32 * 288; ol0 = (chunk - 6) * 16; }
  else if (chunk < 12) { src = wk2c2 + (size_t)br * 64 * 288; ol0 = (chunk - 8) * 16; }
  else                 { src = wconv + (size_t)br * 32 * 288; ol0 = (chunk - 12) * 16; }
  int o = ol0 + (lane & 15);
  wpk[idx] = (_Float16)(src[((size_t)o * 32 + c) * 9 + tap]);
}

// ---------------- MFMA conv: 9 shifted K=32 GEMMs; chunk-PAIR outer / pf inner ----------------
// R16 lesson: bfr[4][9] (144 VGPR) can never stay resident (allocator picks ~104);
// restructure so only af0/af1 (72 VGPR) live across the pf loop and bfr[9] is transient.
template <int MODE>
__global__ __launch_bounds__(256, 2) void conv_mfma_kernel(
    const float* __restrict__ xin, const _Float16* __restrict__ wAll,
    const float* __restrict__ pstat, const float* __restrict__ a_pre,
    int brBase, float* __restrict__ slabBase, size_t slabStride,
    _Float16* __restrict__ vb0, size_t vstrideH) {
  const int NCHUNK = (MODE == 0) ? 14 : 4;
  int bz = blockIdx.z;
  int br = brBase + bz;
  float* slab = slabBase + (size_t)bz * slabStride;
  __shared__ _Float16 hsh[6 * 66 * 36];  // [row6][col66][c-pad36]
  __shared__ float alsh[32], besh[32];
  int tid = threadIdx.x;
  int b = blockIdx.y, r0 = blockIdx.x * 4;
  int ch0 = (br & 1) * 32;
  if (MODE == 0 && tid < 32) {  // reduce x-stats + fold bn/shortcut into affine
    float s = 0.f, s2 = 0.f;
    for (int bb = 0; bb < 32; bb++) {
      size_t p = ((size_t)bb * 64 + ch0 + tid) * 2;
      s += pstat[p]; s2 += pstat[p + 1];
    }
    const float N = 131072.f;
    float m = s / N;
    float r = rsqrtf(s2 / N - m * m + EPSV);
    alsh[tid] = 0.5f * r + 0.01f * a_pre[br];
    besh[tid] = -0.5f * m * r;
  }
  __syncthreads();
  for (int t = tid; t < 384; t += 256) {  // zero halo cols
    int row = t >> 6, colh = ((t & 63) >> 5) ? 65 : 0, c = t & 31;
    hsh[(row * 66 + colh) * 36 + c] = (_Float16)0.f;
  }
  if (MODE == 0) {
    for (int t = tid; t < 32 * 96; t += 256) {  // float4 staging + affine
      int c = t / 96, p4 = (t % 96) * 4;
      int row = p4 >> 6, col = p4 & 63;
      int rg = r0 + row - 1;
      float4 v4 = {0.f, 0.f, 0.f, 0.f};
      if ((unsigned)rg < 64u)
        v4 = *(const float4*)&xin[((size_t)b * 64 + ch0 + c) * HW + (rg << 6) + col];
      float a = alsh[c], be = besh[c];
      _Float16* dst = &hsh[((size_t)row * 66 + col + 1) * 36 + c];
      dst[0]   = (_Float16)(v4.x * a + be);
      dst[36]  = (_Float16)(v4.y * a + be);
      dst[72]  = (_Float16)(v4.z * a + be);
      dst[108] = (_Float16)(v4.w * a + be);
    }
  } else {
    const _Float16* cin = (const _Float16*)(slab + OFF_CCB);
    for (int t = tid; t < 32 * 48; t += 256) {  // 16B staging
      int c = t / 48, p8 = (t % 48) * 8;
      int row = p8 >> 6, col = p8 & 63;
      int rg = r0 + row - 1;
      H8 v; v.u4 = make_uint4(0, 0, 0, 0);
      if ((unsigned)rg < 64u)
        v.u4 = *(const uint4*)&cin[((size_t)b * 32 + c) * HW + (rg << 6) + col];
      _Float16* dst = &hsh[((size_t)row * 66 + col + 1) * 36 + c];
      #pragma unroll
      for (int k = 0; k < 8; k++) dst[36 * k] = v.v[k];
    }
  }
  __syncthreads();
  int w = tid >> 6, l = tid & 63;
  int ln = l & 15, g = l >> 4;
  const _Float16* wb = (MODE == 0)
      ? wAll + (size_t)br * 64512
      : wAll + (size_t)br * 589824 + (size_t)b * 18432;
  for (int cp = 0; cp < NCHUNK / 2; cp++) {
    int c0 = 2 * cp, c1 = 2 * cp + 1;
    H8 af0[9], af1[9];
    #pragma unroll
    for (int t = 0; t < 9; t++) {
      af0[t].u4 = *(const uint4*)(wb + (((size_t)c0 * 9 + t) * 64 + l) * 8);
      af1[t].u4 = *(const uint4*)(wb + (((size_t)c1 * 9 + t) * 64 + l) * 8);
    }
    _Float16 *ob0, *ob1; int Cb0, Cb1, olA, olB;
    if (MODE == 0) {
      // chunk->buffer map (boundaries at even chunks; pairs never straddle)
      if (c0 < 2)       { ob0 = (_Float16*)(slab + OFF_Y1A); Cb0 = 32; olA = c0 * 16; }
      else if (c0 < 6)  { ob0 = (_Float16*)(slab + OFF_Y1B); Cb0 = 64; olA = (c0 - 2) * 16; }
      else if (c0 < 8)  { ob0 = (_Float16*)(slab + OFF_Y2A); Cb0 = 32; olA = (c0 - 6) * 16; }
      else if (c0 < 12) { ob0 = (_Float16*)(slab + OFF_Y2B); Cb0 = 64; olA = (c0 - 8) * 16; }
      else              { ob0 = (_Float16*)(slab + OFF_CCB); Cb0 = 32; olA = (c0 - 12) * 16; }
      ob1 = ob0; Cb1 = Cb0; olB = olA + 16;
    } else {
      ob0 = vb0 + (size_t)br * vstrideH; Cb0 = 64; olA = c0 * 16;
      ob1 = ob0; Cb1 = 64; olB = c1 * 16;
    }
    #pragma unroll
    for (int pf = 0; pf < 4; pf++) {
      H8 bfr[9];
      #pragma unroll
      for (int dyi = 0; dyi < 3; dyi++)
        #pragma unroll
        for (int dxi = 0; dxi < 3; dxi++) {
          const _Float16* p = &hsh[(((size_t)(w + dyi)) * 66 + pf * 16 + ln + dxi) * 36 + 4 * g];
          H8 f;
          f.q[0] = *(const ushort4*)p;
          f.q[1] = *(const ushort4*)(p + 16);
          bfr[dyi * 3 + dxi] = f;
        }
      f32x4 a0 = {0.f, 0.f, 0.f, 0.f}, a1 = {0.f, 0.f, 0.f, 0.f};
      #pragma unroll
      for (int t = 0; t < 9; t++) {
        a0 = __builtin_amdgcn_mfma_f32_16x16x32_f16(bfr[t].v, af0[t].v, a0, 0, 0, 0);
        a1 = __builtin_amdgcn_mfma_f32_16x16x32_f16(bfr[t].v, af1[t].v, a1, 0, 0, 0);
      }
      int px = ((r0 + w) << 6) + pf * 16 + 4 * g;
      union { _Float16 h[4]; ushort4 u; } sv0, sv1;
      #pragma unroll
      for (int j = 0; j < 4; j++) { sv0.h[j] = (_Float16)a0[j]; sv1.h[j] = (_Float16)a1[j]; }
      *(ushort4*)&ob0[((size_t)b * Cb0 + olA + ln) * HW + px] = sv0.u;
      *(ushort4*)&ob1[((size_t)b * Cb1 + olB + ln) * HW + px] = sv1.u;
    }
  }
}

// ---------------- attn1 MFMA: all 9 kk per block; 9 rows per block, dj-compacted LDS ----------------
// grid (7, 32, nslab); partials part1[rg][b][kk][o][i]  (P1 aliases dead y2a/y2b)
__global__ __launch_bounds__(256) void attn1_mfma_kernel(
    float* __restrict__ slabBase, size_t slabStride) {
  __shared__ _Float16 comp[3][96][34];  // [dj][ch 0-31=y1(i),32-95=y2(o)][q padded]
  int rg = blockIdx.x, b = blockIdx.y;
  float* slab = slabBase + (size_t)blockIdx.z * slabStride;
  const _Float16* y1 = (const _Float16*)(slab + OFF_Y1A);
  const _Float16* y2 = (const _Float16*)(slab + OFF_Y1B);
  int tid = threadIdx.x;
  for (int t = tid; t < 4896; t += 256) ((unsigned int*)comp)[t] = 0u;  // zero incl. q-pad
  int w = tid >> 6, lr = tid & 15, g = (tid >> 4) & 3;
  f32x4 acc[9][2];
  #pragma unroll
  for (int kk = 0; kk < 9; kk++) {
    acc[kk][0] = (f32x4){0.f, 0.f, 0.f, 0.f};
    acc[kk][1] = (f32x4){0.f, 0.f, 0.f, 0.f};
  }
  for (int tri = 0; tri < 3; tri++) {
    #pragma unroll
    for (int ri = 0; ri < 3; ri++) {  // di == ri (row base multiple of 3)
      int r = rg * 9 + tri * 3 + ri;
      __syncthreads();
      // stage row r, compacted by dj: each task = (ch, octet of 8 q's)
      for (int t = tid; t < 288; t += 256) {
        int ch = t / 3, oct = t % 3;
        const _Float16* src =
            (ch < 32 ? y1 + ((size_t)b * 32 + ch) * HW
                     : y2 + ((size_t)b * 64 + (ch - 32)) * HW) + (r << 6) + oct * 24;
        union { uint4 q[3]; ushort u[24]; } dat;
        dat.q[0] = *(const uint4*)(src);
        dat.q[1] = *(const uint4*)(src + 8);
        dat.q[2] = *(const uint4*)(src + 16);
        #pragma unroll
        for (int dj = 0; dj < 3; dj++) {
          union { ushort u[8]; uint4 q; } o_;
          #pragma unroll
          for (int m = 0; m < 8; m++) o_.u[m] = dat.u[dj + 3 * m];
          if (oct == 2) { o_.u[5] = 0; o_.u[6] = 0; o_.u[7] = 0; }  // q>20 invalid
          *(uint4*)&comp[dj][ch][oct * 8] = o_.q;
        }
      }
      __syncthreads();
      #pragma unroll
      for (int dj = 0; dj < 3; dj++) {
        H8 af, bf0, bf1;
        const _Float16* pa = &comp[dj][32 + 16 * w + lr][4 * g];
        af.q[0] = *(const ushort4*)pa;  af.q[1] = *(const ushort4*)(pa + 16);
        const _Float16* p0 = &comp[dj][lr][4 * g];
        bf0.q[0] = *(const ushort4*)p0; bf0.q[1] = *(const ushort4*)(p0 + 16);
        const _Float16* p1 = &comp[dj][16 + lr][4 * g];
        bf1.q[0] = *(const ushort4*)p1; bf1.q[1] = *(const ushort4*)(p1 + 16);
        acc[ri * 3 + dj][0] =
            __builtin_amdgcn_mfma_f32_16x16x32_f16(af.v, bf0.v, acc[ri * 3 + dj][0], 0, 0, 0);
        acc[ri * 3 + dj][1] =
            __builtin_amdgcn_mfma_f32_16x16x32_f16(af.v, bf1.v, acc[ri * 3 + dj][1], 0, 0, 0);
      }
    }
  }
  float* part = slab + OFF_P1;  // [rg][b][kk][o][i]
  #pragma unroll
  for (int kk = 0; kk < 9; kk++) {
    size_t base = (((size_t)rg * 32 + b) * 9 + kk) * 2048 + (16 * w + 4 * g) * 32 + lr;
    #pragma unroll
    for (int j = 0; j < 4; j++) {
      part[base + (size_t)j * 32] = acc[kk][0][j];
      part[base + (size_t)j * 32 + 16] = acc[kk][1][j];
    }
  }
}

// ---------------- attn2 MFMA: split-K over 8 pixel segments, vectorized staging ----------------
// grid (8, 32, nslab); partials part2[ps][b][o*32+i]   (runs BEFORE attn1)
__global__ __launch_bounds__(256) void attn2_mfma_kernel(
    float* __restrict__ slabBase, size_t slabStride) {
  __shared__ _Float16 comp[96][68];
  int ps = blockIdx.x, b = blockIdx.y;
  float* slab = slabBase + (size_t)blockIdx.z * slabStride;
  const _Float16* y1 = (const _Float16*)(slab + OFF_Y2A);
  const _Float16* y2 = (const _Float16*)(slab + OFF_Y2B);
  int tid = threadIdx.x;
  int w = tid >> 6, lr = tid & 15, g = (tid >> 4) & 3;
  f32x4 acc0 = {0.f, 0.f, 0.f, 0.f}, acc1 = {0.f, 0.f, 0.f, 0.f};
  for (int st = 0; st < 8; st++) {
    __syncthreads();
    #pragma unroll
    for (int t0 = 0; t0 < 3; t0++) {
      int t = tid + t0 * 256;  // 768 tasks: (ch, 8px part)
      int ch = t >> 3, part = t & 7;
      const _Float16* src =
          (ch < 32 ? y1 + ((size_t)b * 32 + ch) * HW
                   : y2 + ((size_t)b * 64 + (ch - 32)) * HW) + ps * 512 + st * 64 + part * 8;
      *(uint4*)&comp[ch][part * 8] = *(const uint4*)src;
    }
    __syncthreads();
    #pragma unroll
    for (int kh = 0; kh < 2; kh++) {
      H8 af, bf0, bf1;
      const _Float16* pa = &comp[32 + 16 * w + lr][kh * 32 + 4 * g];
      af.q[0] = *(const ushort4*)pa;  af.q[1] = *(const ushort4*)(pa + 16);
      const _Float16* p0 = &comp[lr][kh * 32 + 4 * g];
      bf0.q[0] = *(const ushort4*)p0; bf0.q[1] = *(const ushort4*)(p0 + 16);
      const _Float16* p1 = &comp[16 + lr][kh * 32 + 4 * g];
      bf1.q[0] = *(const ushort4*)p1; bf1.q[1] = *(const ushort4*)(p1 + 16);
      acc0 = __builtin_amdgcn_mfma_f32_16x16x32_f16(af.v, bf0.v, acc0, 0, 0, 0);
      acc1 = __builtin_amdgcn_mfma_f32_16x16x32_f16(af.v, bf1.v, acc1, 0, 0, 0);
    }
  }
  float* p2 = slab + OFF_P2;
  size_t base = ((size_t)ps * 32 + b) * 2048 + (16 * w + 4 * g) * 32 + lr;
  #pragma unroll
  for (int j = 0; j < 4; j++) {
    p2[base + (size_t)j * 32] = acc0[j];
    p2[base + (size_t)j * 32 + 16] = acc1[j];
  }
}

// ---------------- fused: reduce partials + softmax + ak + pack ----------------
__global__ __launch_bounds__(320) void fused_ak_kernel(
    float* __restrict__ slabBase, size_t slabStride, int brBase,
    const float* __restrict__ aw, _Float16* __restrict__ wdynB) {
  int o = blockIdx.x, b = blockIdx.y;
  int bz = blockIdx.z, br = brBase + bz;
  float* slab = slabBase + (size_t)bz * slabStride;
  const float* part1 = slab + OFF_P1;
  const float* part2 = slab + OFF_P2;
  const float* awb = aw + (size_t)br * 18432;
  _Float16* wdyn = wdynB + (size_t)br * 589824;
  int tid = threadIdx.x;
  __shared__ float sm[33];
  if (tid < 32) {
    float s = 0.f;
    #pragma unroll
    for (int ps = 0; ps < 8; ps++) s += part2[((size_t)ps * 32 + b) * 2048 + o * 32 + tid];
    sm[tid] = s * 0.17677669529663687f;  // 1/sqrt(32)
  }
  __syncthreads();
  if (tid == 0) {
    float mx = -1e30f;
    for (int k = 0; k < 32; k++) mx = fmaxf(mx, sm[k]);
    float sum = 0.f;
    for (int k = 0; k < 32; k++) { float e = expf(sm[k] - mx); sm[k] = e; sum += e; }
    sm[32] = 1.0f / sum;
  }
  __syncthreads();
  if (tid < 288) {
    int i = tid / 9, kk = tid % 9;
    float a1v = 0.f;
    #pragma unroll
    for (int rg = 0; rg < 7; rg++)
      a1v += part1[(((size_t)rg * 32 + b) * 9 + kk) * 2048 + o * 32 + i];
    a1v *= 0.05892556509887896f;  // 1/sqrt(288)
    float akv = sm[i] * sm[32] * (a1v + awb[(size_t)(o * 32 + i) * 9 + kk]);
    int chunk = o >> 4;
    int g = (i & 15) >> 2;
    int j = (i & 3) + ((i >= 16) ? 4 : 0);
    int lane = (g << 4) | (o & 15);
    wdyn[((((size_t)b * 4 + chunk) * 9 + kk) * 64 + lane) * 8 + j] = (_Float16)akv;
  }
}

// ---------------- fused finalize: v-stats reduce + 4-branch combine ----------------
__global__ __launch_bounds__(256) void finalize_kernel(
    const _Float16* __restrict__ vb0, size_t vstrideH,
    const float* __restrict__ pstat, const float* __restrict__ a_post,
    const float* __restrict__ x, const float* __restrict__ cm,
    float* __restrict__ out) {
  __shared__ float sga[256], sgb[256];
  int t = threadIdx.x;
  {
    int br = t >> 6, o = t & 63;
    float s = 0.f, s2 = 0.f;
    for (int bb = 0; bb < 32; bb++) {
      size_t p = (((size_t)br * 32 + bb) * 64 + o) * 2;
      s += pstat[p]; s2 += pstat[p + 1];
    }
    const float N = 131072.f;
    float m = s / N;
    float r = rsqrtf(s2 / N - m * m + EPSV);
    sga[t] = 0.5f * r + 0.6f * a_post[br];
    sgb[t] = -0.5f * m * r;
  }
  __syncthreads();
  size_t g8 = ((size_t)blockIdx.x * 256 + threadIdx.x) * 8;
  int o = (int)((g8 >> 12) & 63);
  float acc[8], ysv[8];
  #pragma unroll
  for (int br = 0; br < 4; br++) {
    float ga = sga[br * 64 + o], gb = sgb[br * 64 + o];
    H8 v; v.u4 = *(const uint4*)(vb0 + (size_t)br * vstrideH + g8);
    #pragma unroll
    for (int j = 0; j < 8; j++) {
      float y = ga * (float)v.v[j] + gb;
      if (br == 0) acc[j] = y;
      else if (br == 1) acc[j] += y;
      else if (br == 2) ysv[j] = y;
      else acc[j] += ysv[j] * y;
    }
  }
  float cmv = 0.99f * cm[0];
  const float4* xp = (const float4*)(x + g8);
  float4 x0 = xp[0], x1 = xp[1];
  float4 o0, o1;
  o0.x = cmv * x0.x + acc[0] * 0.5773502691896258f;
  o0.y = cmv * x0.y + acc[1] * 0.5773502691896258f;
  o0.z = cmv * x0.z + acc[2] * 0.5773502691896258f;
  o0.w = cmv * x0.w + acc[3] * 0.5773502691896258f;
  o1.x = cmv * x1.x + acc[4] * 0.5773502691896258f;
  o1.y = cmv * x1.y + acc[5] * 0.5773502691896258f;
  o1.z = cmv * x1.z + acc[6] * 0.5773502691896258f;
  o1.w = cmv * x1.w + acc[7] * 0.5773502691896258f;
  float4* op = (float4*)(out + g8);
  op[0] = o0;
  op[1] = o1;
}

extern "C" void kernel_launch(void* const* d_in, const int* in_sizes, int n_in,
                              void* d_out, int out_size, void* d_ws, size_t ws_size,
                              hipStream_t stream) {
  const float* x      = (const float*)d_in[0];
  const float* wk1c1  = (const float*)d_in[1];
  const float* wk1c2  = (const float*)d_in[2];
  const float* wk2c1  = (const float*)d_in[3];
  const float* wk2c2  = (const float*)d_in[4];
  const float* wconv  = (const float*)d_in[5];
  const float* attn_w = (const float*)d_in[6];
  const float* a_pre  = (const float*)d_in[7];
  const float* a_post = (const float*)d_in[8];
  const float* cm     = (const float*)d_in[9];
  float* out = (float*)d_out;

  const size_t FIX_F  = 129024ull + 1179648ull + 16384ull;  // wpk + wdyn + pstat
  const size_t VBUF_F = 16777216ull;                        // fallback-only dedicated vbuf
  size_t wsF = ws_size / 4;
  int nslab;
  if (wsF >= 4 * SLAB_F + FIX_F) nslab = 4;
  else if (wsF >= 2 * SLAB_F + FIX_F + VBUF_F) nslab = 2;
  else nslab = 1;

  float* ws = (float*)d_ws;
  float* slab0 = ws;
  float* fixF  = ws + (size_t)nslab * SLAB_F;
  _Float16* wpk   = (_Float16*)fixF;
  _Float16* wdynB = (_Float16*)(fixF + 129024);
  float* pstat    = fixF + 129024 + 1179648;
  // vbuf: 4-slab path aliases each slab's dead y1a region; fallback uses dedicated region
  _Float16* vb0;
  size_t VSH;
  if (nslab == 4) { vb0 = (_Float16*)(slab0 + OFF_Y1A); VSH = SLAB_F * 2; }
  else            { vb0 = (_Float16*)(fixF + FIX_F);    VSH = 8388608ull; }

  bn_partial_kernel<<<dim3(64, 32), 256, 0, stream>>>(x, pstat);
  pack_static_kernel<<<1008, 256, 0, stream>>>(wk1c1, wk1c2, wk2c1, wk2c2, wconv, wpk);

  for (int b0 = 0; b0 < 4; b0 += nslab) {
    conv_mfma_kernel<0><<<dim3(16, 32, nslab), 256, 0, stream>>>(
        x, wpk, pstat, a_pre, b0, slab0, SLAB_F, nullptr, 0);
    // attn2 first: frees y2a/y2b so attn1's P1 (aliasing them) is safe
    attn2_mfma_kernel<<<dim3(8, 32, nslab), 256, 0, stream>>>(slab0, SLAB_F);
    attn1_mfma_kernel<<<dim3(7, 32, nslab), 256, 0, stream>>>(slab0, SLAB_F);
    fused_ak_kernel<<<dim3(64, 32, nslab), 320, 0, stream>>>(
        slab0, SLAB_F, b0, attn_w, wdynB);
    conv_mfma_kernel<1><<<dim3(16, 32, nslab), 256, 0, stream>>>(
        nullptr, wdynB, nullptr, nullptr, b0, slab0, SLAB_F, vb0, VSH);
  }

  bnv_partial_kernel<<<dim3(64, 32, 4), 256, 0, stream>>>(vb0, VSH, pstat);
  finalize_kernel<<<4096, 256, 0, stream>>>(vb0, VSH, pstat, a_post, x, cm, out);
}

// Round 18
// 373.680 us; speedup vs baseline: 1.0087x; 1.0087x over previous
//
#include <hip/hip_runtime.h>
#include <math.h>

#define HW 4096
#define EPSV 1e-5f

typedef _Float16 half8 __attribute__((ext_vector_type(8)));
typedef float f32x4 __attribute__((ext_vector_type(4)));
union H8 { half8 v; ushort4 q[2]; uint4 u4; };

// slab layout (float offsets) — lifetime-aliased, 15,204,352 floats/slab
#define SLAB_F  15204352ull
#define OFF_Y1A 0
#define OFF_Y1B 2097152
#define OFF_Y2A 6291456
#define OFF_Y2B 8388608
#define OFF_CCB 12582912
#define OFF_P2  14680064
#define OFF_P1  6291456

// ---------------- bn stats over x: one (b,c) plane per block, float4 ----------------
__global__ __launch_bounds__(256) void bn_partial_kernel(
    const float* __restrict__ x, float* __restrict__ pstat) {
  int c = blockIdx.x, b = blockIdx.y;
  int tid = threadIdx.x;
  const float4* p = (const float4*)(x + ((size_t)b * 64 + c) * HW);
  float sm = 0.f, s2 = 0.f;
  #pragma unroll
  for (int i = 0; i < 4; i++) {
    float4 v = p[tid + i * 256];
    sm += v.x + v.y + v.z + v.w;
    s2 += v.x * v.x + v.y * v.y + v.z * v.z + v.w * v.w;
  }
  __shared__ float sh[2][256];
  sh[0][tid] = sm; sh[1][tid] = s2;
  __syncthreads();
  for (int off = 128; off > 0; off >>= 1) {
    if (tid < off) { sh[0][tid] += sh[0][tid + off]; sh[1][tid] += sh[1][tid + off]; }
    __syncthreads();
  }
  if (tid == 0) {
    pstat[((size_t)b * 64 + c) * 2] = sh[0][0];
    pstat[((size_t)b * 64 + c) * 2 + 1] = sh[1][0];
  }
}

// ---------------- bn stats over v (f16): one (br,b,c) plane per block ----------------
__global__ __launch_bounds__(256) void bnv_partial_kernel(
    const _Float16* __restrict__ vb0, size_t vstrideH, float* __restrict__ pstat) {
  int c = blockIdx.x, b = blockIdx.y, br = blockIdx.z;
  int tid = threadIdx.x;
  const _Float16* row = vb0 + (size_t)br * vstrideH + ((size_t)b * 64 + c) * HW;
  float sm = 0.f, s2 = 0.f;
  #pragma unroll
  for (int i = 0; i < 2; i++) {
    H8 v; v.u4 = *(const uint4*)(row + (tid + i * 256) * 8);
    #pragma unroll
    for (int k = 0; k < 8; k++) { float t = (float)v.v[k]; sm += t; s2 += t * t; }
  }
  __shared__ float sh[2][256];
  sh[0][tid] = sm; sh[1][tid] = s2;
  __syncthreads();
  for (int off = 128; off > 0; off >>= 1) {
    if (tid < off) { sh[0][tid] += sh[0][tid + off]; sh[1][tid] += sh[1][tid + off]; }
    __syncthreads();
  }
  if (tid == 0) {
    pstat[(((size_t)br * 32 + b) * 64 + c) * 2] = sh[0][0];
    pstat[(((size_t)br * 32 + b) * 64 + c) * 2 + 1] = sh[1][0];
  }
}

// ---------------- pack static conv weights into MFMA A-fragment order ----------------
__global__ __launch_bounds__(256) void pack_static_kernel(
    const float* __restrict__ wk1c1, const float* __restrict__ wk1c2,
    const float* __restrict__ wk2c1, const float* __restrict__ wk2c2,
    const float* __restrict__ wconv, _Float16* __restrict__ wpk) {
  int idx = blockIdx.x * 256 + threadIdx.x;  // 258048
  int j = idx & 7, lane = (idx >> 3) & 63;
  int tap = (idx >> 9) % 9;
  int chunk = (idx / 4608) % 14;
  int br = idx / 64512;
  int g = lane >> 4;
  int c = (j < 4) ? 4 * g + j : 16 + 4 * g + (j - 4);
  const float* src; int ol0;
  if (chunk < 2)       { src = wk1c1 + (size_t)br * 32 * 288; ol0 = chunk * 16; }
  else if (chunk < 6)  { src = wk1c2 + (size_t)br * 64 * 288; ol0 = (chunk - 2) * 16; }
  else if (chunk < 8)  { src = wk2c1 + (size_t)br * 32 * 288; ol0 = (chunk - 6) * 16; }
  else if (chunk < 12) { src = wk2c2 + (size_t)br * 64 * 288; ol0 = (chunk - 8) * 16; }
  else                 { src = wconv + (size_t)br * 32 * 288; ol0 = (chunk - 12) * 16; }
  int o = ol0 + (lane & 15);
  wpk[idx] = (_Float16)(src[((size_t)o * 32 + c) * 9 + tap]);
}

// ---------------- MFMA conv: 9 shifted K=32 GEMMs; 512 threads / 8 output rows ----------------
// R16 inner loop kept verbatim (best measured); this round only widens the block:
// 8 waves stage 10 rows (halo 1.25x vs 1.5x) and share one barrier per phase.
template <int MODE>
__global__ __launch_bounds__(512, 1) void conv_mfma_kernel(
    const float* __restrict__ xin, const _Float16* __restrict__ wAll,
    const float* __restrict__ pstat, const float* __restrict__ a_pre,
    int brBase, float* __restrict__ slabBase, size_t slabStride,
    _Float16* __restrict__ vb0, size_t vstrideH) {
  const int NCHUNK = (MODE == 0) ? 14 : 4;
  int bz = blockIdx.z;
  int br = brBase + bz;
  float* slab = slabBase + (size_t)bz * slabStride;
  __shared__ _Float16 hsh[10 * 66 * 36];  // [row10][col66][c-pad36]
  __shared__ float alsh[32], besh[32];
  int tid = threadIdx.x;
  int b = blockIdx.y, r0 = blockIdx.x * 8;
  int ch0 = (br & 1) * 32;
  if (MODE == 0 && tid < 32) {  // reduce x-stats + fold bn/shortcut into affine
    float s = 0.f, s2 = 0.f;
    for (int bb = 0; bb < 32; bb++) {
      size_t p = ((size_t)bb * 64 + ch0 + tid) * 2;
      s += pstat[p]; s2 += pstat[p + 1];
    }
    const float N = 131072.f;
    float m = s / N;
    float r = rsqrtf(s2 / N - m * m + EPSV);
    alsh[tid] = 0.5f * r + 0.01f * a_pre[br];
    besh[tid] = -0.5f * m * r;
  }
  __syncthreads();
  for (int t = tid; t < 640; t += 512) {  // zero halo cols (10 rows x {0,65} x 32c)
    int row = t >> 6, colh = ((t & 63) >> 5) ? 65 : 0, c = t & 31;
    hsh[(row * 66 + colh) * 36 + c] = (_Float16)0.f;
  }
  if (MODE == 0) {
    for (int t = tid; t < 32 * 160; t += 512) {  // float4 staging + affine (10 rows)
      int c = t / 160, p4 = (t % 160) * 4;
      int row = p4 >> 6, col = p4 & 63;
      int rg = r0 + row - 1;
      float4 v4 = {0.f, 0.f, 0.f, 0.f};
      if ((unsigned)rg < 64u)
        v4 = *(const float4*)&xin[((size_t)b * 64 + ch0 + c) * HW + (rg << 6) + col];
      float a = alsh[c], be = besh[c];
      _Float16* dst = &hsh[((size_t)row * 66 + col + 1) * 36 + c];
      dst[0]   = (_Float16)(v4.x * a + be);
      dst[36]  = (_Float16)(v4.y * a + be);
      dst[72]  = (_Float16)(v4.z * a + be);
      dst[108] = (_Float16)(v4.w * a + be);
    }
  } else {
    const _Float16* cin = (const _Float16*)(slab + OFF_CCB);
    for (int t = tid; t < 32 * 80; t += 512) {  // 16B staging (10 rows)
      int c = t / 80, p8 = (t % 80) * 8;
      int row = p8 >> 6, col = p8 & 63;
      int rg = r0 + row - 1;
      H8 v; v.u4 = make_uint4(0, 0, 0, 0);
      if ((unsigned)rg < 64u)
        v.u4 = *(const uint4*)&cin[((size_t)b * 32 + c) * HW + (rg << 6) + col];
      _Float16* dst = &hsh[((size_t)row * 66 + col + 1) * 36 + c];
      #pragma unroll
      for (int k = 0; k < 8; k++) dst[36 * k] = v.v[k];
    }
  }
  __syncthreads();
  int w = tid >> 6, l = tid & 63;  // w = 0..7 output row within tile
  int ln = l & 15, g = l >> 4;
  H8 bfr[4][9];
  #pragma unroll
  for (int pf = 0; pf < 4; pf++)
    #pragma unroll
    for (int dyi = 0; dyi < 3; dyi++)
      #pragma unroll
      for (int dxi = 0; dxi < 3; dxi++) {
        const _Float16* p = &hsh[(((size_t)(w + dyi)) * 66 + pf * 16 + ln + dxi) * 36 + 4 * g];
        H8 f;
        f.q[0] = *(const ushort4*)p;
        f.q[1] = *(const ushort4*)(p + 16);
        bfr[pf][dyi * 3 + dxi] = f;
      }
  const _Float16* wb = (MODE == 0)
      ? wAll + (size_t)br * 64512
      : wAll + (size_t)br * 589824 + (size_t)b * 18432;
  for (int chunk = 0; chunk < NCHUNK; chunk++) {
    H8 af[9];
    #pragma unroll
    for (int t = 0; t < 9; t++)
      af[t].u4 = *(const uint4*)(wb + (((size_t)chunk * 9 + t) * 64 + l) * 8);
    _Float16* ob; int Cb, ol0;
    if (MODE == 0) {
      if (chunk < 2)       { ob = (_Float16*)(slab + OFF_Y1A); Cb = 32; ol0 = chunk * 16; }
      else if (chunk < 6)  { ob = (_Float16*)(slab + OFF_Y1B); Cb = 64; ol0 = (chunk - 2) * 16; }
      else if (chunk < 8)  { ob = (_Float16*)(slab + OFF_Y2A); Cb = 32; ol0 = (chunk - 6) * 16; }
      else if (chunk < 12) { ob = (_Float16*)(slab + OFF_Y2B); Cb = 64; ol0 = (chunk - 8) * 16; }
      else                 { ob = (_Float16*)(slab + OFF_CCB); Cb = 32; ol0 = (chunk - 12) * 16; }
    } else { ob = vb0 + (size_t)br * vstrideH; Cb = 64; ol0 = chunk * 16; }
    #pragma unroll
    for (int pf = 0; pf < 4; pf++) {
      f32x4 acc = {0.f, 0.f, 0.f, 0.f};
      #pragma unroll
      for (int t = 0; t < 9; t++)
        acc = __builtin_amdgcn_mfma_f32_16x16x32_f16(bfr[pf][t].v, af[t].v, acc, 0, 0, 0);
      union { _Float16 h[4]; ushort4 u; } sv;
      #pragma unroll
      for (int j = 0; j < 4; j++) sv.h[j] = (_Float16)acc[j];
      int px = ((r0 + w) << 6) + pf * 16 + 4 * g;
      *(ushort4*)&ob[((size_t)b * Cb + ol0 + ln) * HW + px] = sv.u;
    }
  }
}

// ---------------- attn1 MFMA: all 9 kk per block; 9 rows per block, dj-compacted LDS ----------------
// grid (7, 32, nslab); partials part1[rg][b][kk][o][i]  (P1 aliases dead y2a/y2b)
__global__ __launch_bounds__(256) void attn1_mfma_kernel(
    float* __restrict__ slabBase, size_t slabStride) {
  __shared__ _Float16 comp[3][96][34];  // [dj][ch 0-31=y1(i),32-95=y2(o)][q padded]
  int rg = blockIdx.x, b = blockIdx.y;
  float* slab = slabBase + (size_t)blockIdx.z * slabStride;
  const _Float16* y1 = (const _Float16*)(slab + OFF_Y1A);
  const _Float16* y2 = (const _Float16*)(slab + OFF_Y1B);
  int tid = threadIdx.x;
  for (int t = tid; t < 4896; t += 256) ((unsigned int*)comp)[t] = 0u;  // zero incl. q-pad
  int w = tid >> 6, lr = tid & 15, g = (tid >> 4) & 3;
  f32x4 acc[9][2];
  #pragma unroll
  for (int kk = 0; kk < 9; kk++) {
    acc[kk][0] = (f32x4){0.f, 0.f, 0.f, 0.f};
    acc[kk][1] = (f32x4){0.f, 0.f, 0.f, 0.f};
  }
  for (int tri = 0; tri < 3; tri++) {
    #pragma unroll
    for (int ri = 0; ri < 3; ri++) {  // di == ri (row base multiple of 3)
      int r = rg * 9 + tri * 3 + ri;
      __syncthreads();
      // stage row r, compacted by dj: each task = (ch, octet of 8 q's)
      for (int t = tid; t < 288; t += 256) {
        int ch = t / 3, oct = t % 3;
        const _Float16* src =
            (ch < 32 ? y1 + ((size_t)b * 32 + ch) * HW
                     : y2 + ((size_t)b * 64 + (ch - 32)) * HW) + (r << 6) + oct * 24;
        union { uint4 q[3]; ushort u[24]; } dat;
        dat.q[0] = *(const uint4*)(src);
        dat.q[1] = *(const uint4*)(src + 8);
        dat.q[2] = *(const uint4*)(src + 16);
        #pragma unroll
        for (int dj = 0; dj < 3; dj++) {
          union { ushort u[8]; uint4 q; } o_;
          #pragma unroll
          for (int m = 0; m < 8; m++) o_.u[m] = dat.u[dj + 3 * m];
          if (oct == 2) { o_.u[5] = 0; o_.u[6] = 0; o_.u[7] = 0; }  // q>20 invalid
          *(uint4*)&comp[dj][ch][oct * 8] = o_.q;
        }
      }
      __syncthreads();
      #pragma unroll
      for (int dj = 0; dj < 3; dj++) {
        H8 af, bf0, bf1;
        const _Float16* pa = &comp[dj][32 + 16 * w + lr][4 * g];
        af.q[0] = *(const ushort4*)pa;  af.q[1] = *(const ushort4*)(pa + 16);
        const _Float16* p0 = &comp[dj][lr][4 * g];
        bf0.q[0] = *(const ushort4*)p0; bf0.q[1] = *(const ushort4*)(p0 + 16);
        const _Float16* p1 = &comp[dj][16 + lr][4 * g];
        bf1.q[0] = *(const ushort4*)p1; bf1.q[1] = *(const ushort4*)(p1 + 16);
        acc[ri * 3 + dj][0] =
            __builtin_amdgcn_mfma_f32_16x16x32_f16(af.v, bf0.v, acc[ri * 3 + dj][0], 0, 0, 0);
        acc[ri * 3 + dj][1] =
            __builtin_amdgcn_mfma_f32_16x16x32_f16(af.v, bf1.v, acc[ri * 3 + dj][1], 0, 0, 0);
      }
    }
  }
  float* part = slab + OFF_P1;  // [rg][b][kk][o][i]
  #pragma unroll
  for (int kk = 0; kk < 9; kk++) {
    size_t base = (((size_t)rg * 32 + b) * 9 + kk) * 2048 + (16 * w + 4 * g) * 32 + lr;
    #pragma unroll
    for (int j = 0; j < 4; j++) {
      part[base + (size_t)j * 32] = acc[kk][0][j];
      part[base + (size_t)j * 32 + 16] = acc[kk][1][j];
    }
  }
}

// ---------------- attn2 MFMA: split-K over 8 pixel segments, vectorized staging ----------------
// grid (8, 32, nslab); partials part2[ps][b][o*32+i]   (runs BEFORE attn1)
__global__ __launch_bounds__(256) void attn2_mfma_kernel(
    float* __restrict__ slabBase, size_t slabStride) {
  __shared__ _Float16 comp[96][68];
  int ps = blockIdx.x, b = blockIdx.y;
  float* slab = slabBase + (size_t)blockIdx.z * slabStride;
  const _Float16* y1 = (const _Float16*)(slab + OFF_Y2A);
  const _Float16* y2 = (const _Float16*)(slab + OFF_Y2B);
  int tid = threadIdx.x;
  int w = tid >> 6, lr = tid & 15, g = (tid >> 4) & 3;
  f32x4 acc0 = {0.f, 0.f, 0.f, 0.f}, acc1 = {0.f, 0.f, 0.f, 0.f};
  for (int st = 0; st < 8; st++) {
    __syncthreads();
    #pragma unroll
    for (int t0 = 0; t0 < 3; t0++) {
      int t = tid + t0 * 256;  // 768 tasks: (ch, 8px part)
      int ch = t >> 3, part = t & 7;
      const _Float16* src =
          (ch < 32 ? y1 + ((size_t)b * 32 + ch) * HW
                   : y2 + ((size_t)b * 64 + (ch - 32)) * HW) + ps * 512 + st * 64 + part * 8;
      *(uint4*)&comp[ch][part * 8] = *(const uint4*)src;
    }
    __syncthreads();
    #pragma unroll
    for (int kh = 0; kh < 2; kh++) {
      H8 af, bf0, bf1;
      const _Float16* pa = &comp[32 + 16 * w + lr][kh * 32 + 4 * g];
      af.q[0] = *(const ushort4*)pa;  af.q[1] = *(const ushort4*)(pa + 16);
      const _Float16* p0 = &comp[lr][kh * 32 + 4 * g];
      bf0.q[0] = *(const ushort4*)p0; bf0.q[1] = *(const ushort4*)(p0 + 16);
      const _Float16* p1 = &comp[16 + lr][kh * 32 + 4 * g];
      bf1.q[0] = *(const ushort4*)p1; bf1.q[1] = *(const ushort4*)(p1 + 16);
      acc0 = __builtin_amdgcn_mfma_f32_16x16x32_f16(af.v, bf0.v, acc0, 0, 0, 0);
      acc1 = __builtin_amdgcn_mfma_f32_16x16x32_f16(af.v, bf1.v, acc1, 0, 0, 0);
    }
  }
  float* p2 = slab + OFF_P2;
  size_t base = ((size_t)ps * 32 + b) * 2048 + (16 * w + 4 * g) * 32 + lr;
  #pragma unroll
  for (int j = 0; j < 4; j++) {
    p2[base + (size_t)j * 32] = acc0[j];
    p2[base + (size_t)j * 32 + 16] = acc1[j];
  }
}

// ---------------- fused: reduce partials + softmax + ak + pack ----------------
__global__ __launch_bounds__(320) void fused_ak_kernel(
    float* __restrict__ slabBase, size_t slabStride, int brBase,
    const float* __restrict__ aw, _Float16* __restrict__ wdynB) {
  int o = blockIdx.x, b = blockIdx.y;
  int bz = blockIdx.z, br = brBase + bz;
  float* slab = slabBase + (size_t)bz * slabStride;
  const float* part1 = slab + OFF_P1;
  const float* part2 = slab + OFF_P2;
  const float* awb = aw + (size_t)br * 18432;
  _Float16* wdyn = wdynB + (size_t)br * 589824;
  int tid = threadIdx.x;
  __shared__ float sm[33];
  if (tid < 32) {
    float s = 0.f;
    #pragma unroll
    for (int ps = 0; ps < 8; ps++) s += part2[((size_t)ps * 32 + b) * 2048 + o * 32 + tid];
    sm[tid] = s * 0.17677669529663687f;  // 1/sqrt(32)
  }
  __syncthreads();
  if (tid == 0) {
    float mx = -1e30f;
    for (int k = 0; k < 32; k++) mx = fmaxf(mx, sm[k]);
    float sum = 0.f;
    for (int k = 0; k < 32; k++) { float e = expf(sm[k] - mx); sm[k] = e; sum += e; }
    sm[32] = 1.0f / sum;
  }
  __syncthreads();
  if (tid < 288) {
    int i = tid / 9, kk = tid % 9;
    float a1v = 0.f;
    #pragma unroll
    for (int rg = 0; rg < 7; rg++)
      a1v += part1[(((size_t)rg * 32 + b) * 9 + kk) * 2048 + o * 32 + i];
    a1v *= 0.05892556509887896f;  // 1/sqrt(288)
    float akv = sm[i] * sm[32] * (a1v + awb[(size_t)(o * 32 + i) * 9 + kk]);
    int chunk = o >> 4;
    int g = (i & 15) >> 2;
    int j = (i & 3) + ((i >= 16) ? 4 : 0);
    int lane = (g << 4) | (o & 15);
    wdyn[((((size_t)b * 4 + chunk) * 9 + kk) * 64 + lane) * 8 + j] = (_Float16)akv;
  }
}

// ---------------- fused finalize: v-stats reduce + 4-branch combine ----------------
__global__ __launch_bounds__(256) void finalize_kernel(
    const _Float16* __restrict__ vb0, size_t vstrideH,
    const float* __restrict__ pstat, const float* __restrict__ a_post,
    const float* __restrict__ x, const float* __restrict__ cm,
    float* __restrict__ out) {
  __shared__ float sga[256], sgb[256];
  int t = threadIdx.x;
  {
    int br = t >> 6, o = t & 63;
    float s = 0.f, s2 = 0.f;
    for (int bb = 0; bb < 32; bb++) {
      size_t p = (((size_t)br * 32 + bb) * 64 + o) * 2;
      s += pstat[p]; s2 += pstat[p + 1];
    }
    const float N = 131072.f;
    float m = s / N;
    float r = rsqrtf(s2 / N - m * m + EPSV);
    sga[t] = 0.5f * r + 0.6f * a_post[br];
    sgb[t] = -0.5f * m * r;
  }
  __syncthreads();
  size_t g8 = ((size_t)blockIdx.x * 256 + threadIdx.x) * 8;
  int o = (int)((g8 >> 12) & 63);
  float acc[8], ysv[8];
  #pragma unroll
  for (int br = 0; br < 4; br++) {
    float ga = sga[br * 64 + o], gb = sgb[br * 64 + o];
    H8 v; v.u4 = *(const uint4*)(vb0 + (size_t)br * vstrideH + g8);
    #pragma unroll
    for (int j = 0; j < 8; j++) {
      float y = ga * (float)v.v[j] + gb;
      if (br == 0) acc[j] = y;
      else if (br == 1) acc[j] += y;
      else if (br == 2) ysv[j] = y;
      else acc[j] += ysv[j] * y;
    }
  }
  float cmv = 0.99f * cm[0];
  const float4* xp = (const float4*)(x + g8);
  float4 x0 = xp[0], x1 = xp[1];
  float4 o0, o1;
  o0.x = cmv * x0.x + acc[0] * 0.5773502691896258f;
  o0.y = cmv * x0.y + acc[1] * 0.5773502691896258f;
  o0.z = cmv * x0.z + acc[2] * 0.5773502691896258f;
  o0.w = cmv * x0.w + acc[3] * 0.5773502691896258f;
  o1.x = cmv * x1.x + acc[4] * 0.5773502691896258f;
  o1.y = cmv * x1.y + acc[5] * 0.5773502691896258f;
  o1.z = cmv * x1.z + acc[6] * 0.5773502691896258f;
  o1.w = cmv * x1.w + acc[7] * 0.5773502691896258f;
  float4* op = (float4*)(out + g8);
  op[0] = o0;
  op[1] = o1;
}

extern "C" void kernel_launch(void* const* d_in, const int* in_sizes, int n_in,
                              void* d_out, int out_size, void* d_ws, size_t ws_size,
                              hipStream_t stream) {
  const float* x      = (const float*)d_in[0];
  const float* wk1c1  = (const float*)d_in[1];
  const float* wk1c2  = (const float*)d_in[2];
  const float* wk2c1  = (const float*)d_in[3];
  const float* wk2c2  = (const float*)d_in[4];
  const float* wconv  = (const float*)d_in[5];
  const float* attn_w = (const float*)d_in[6];
  const float* a_pre  = (const float*)d_in[7];
  const float* a_post = (const float*)d_in[8];
  const float* cm     = (const float*)d_in[9];
  float* out = (float*)d_out;

  const size_t FIX_F  = 129024ull + 1179648ull + 16384ull;  // wpk + wdyn + pstat
  const size_t VBUF_F = 16777216ull;                        // fallback-only dedicated vbuf
  size_t wsF = ws_size / 4;
  int nslab;
  if (wsF >= 4 * SLAB_F + FIX_F) nslab = 4;
  else if (wsF >= 2 * SLAB_F + FIX_F + VBUF_F) nslab = 2;
  else nslab = 1;

  float* ws = (float*)d_ws;
  float* slab0 = ws;
  float* fixF  = ws + (size_t)nslab * SLAB_F;
  _Float16* wpk   = (_Float16*)fixF;
  _Float16* wdynB = (_Float16*)(fixF + 129024);
  float* pstat    = fixF + 129024 + 1179648;
  // vbuf: 4-slab path aliases each slab's dead y1a region; fallback uses dedicated region
  _Float16* vb0;
  size_t VSH;
  if (nslab == 4) { vb0 = (_Float16*)(slab0 + OFF_Y1A); VSH = SLAB_F * 2; }
  else            { vb0 = (_Float16*)(fixF + FIX_F);    VSH = 8388608ull; }

  bn_partial_kernel<<<dim3(64, 32), 256, 0, stream>>>(x, pstat);
  pack_static_kernel<<<1008, 256, 0, stream>>>(wk1c1, wk1c2, wk2c1, wk2c2, wconv, wpk);

  for (int b0 = 0; b0 < 4; b0 += nslab) {
    conv_mfma_kernel<0><<<dim3(8, 32, nslab), 512, 0, stream>>>(
        x, wpk, pstat, a_pre, b0, slab0, SLAB_F, nullptr, 0);
    // attn2 first: frees y2a/y2b so attn1's P1 (aliasing them) is safe
    attn2_mfma_kernel<<<dim3(8, 32, nslab), 256, 0, stream>>>(slab0, SLAB_F);
    attn1_mfma_kernel<<<dim3(7, 32, nslab), 256, 0, stream>>>(slab0, SLAB_F);
    fused_ak_kernel<<<dim3(64, 32, nslab), 320, 0, stream>>>(
        slab0, SLAB_F, b0, attn_w, wdynB);
    conv_mfma_kernel<1><<<dim3(8, 32, nslab), 512, 0, stream>>>(
        nullptr, wdynB, nullptr, nullptr, b0, slab0, SLAB_F, vb0, VSH);
  }

  bnv_partial_kernel<<<dim3(64, 32, 4), 256, 0, stream>>>(vb0, VSH, pstat);
  finalize_kernel<<<4096, 256, 0, stream>>>(vb0, VSH, pstat, a_post, x, cm, out);
}

// Round 20
// 367.088 us; speedup vs baseline: 1.0268x; 1.0180x over previous
//
#include <hip/hip_runtime.h>
#include <math.h>

#define HW 4096
#define EPSV 1e-5f

typedef _Float16 half8 __attribute__((ext_vector_type(8)));
typedef float f32x4 __attribute__((ext_vector_type(4)));
union H8 { half8 v; ushort4 q[2]; uint4 u4; };

// slab layout (float offsets) — lifetime-aliased, 15,204,352 floats/slab
#define SLAB_F  15204352ull
#define OFF_Y1A 0
#define OFF_Y1B 2097152
#define OFF_Y2A 6291456
#define OFF_Y2B 8388608
#define OFF_CCB 12582912
#define OFF_P2  14680064
#define OFF_P1  6291456

// ---------------- bn stats over x: one (b,c) plane per block, float4 ----------------
__global__ __launch_bounds__(256) void bn_partial_kernel(
    const float* __restrict__ x, float* __restrict__ pstat) {
  int c = blockIdx.x, b = blockIdx.y;
  int tid = threadIdx.x;
  const float4* p = (const float4*)(x + ((size_t)b * 64 + c) * HW);
  float sm = 0.f, s2 = 0.f;
  #pragma unroll
  for (int i = 0; i < 4; i++) {
    float4 v = p[tid + i * 256];
    sm += v.x + v.y + v.z + v.w;
    s2 += v.x * v.x + v.y * v.y + v.z * v.z + v.w * v.w;
  }
  __shared__ float sh[2][256];
  sh[0][tid] = sm; sh[1][tid] = s2;
  __syncthreads();
  for (int off = 128; off > 0; off >>= 1) {
    if (tid < off) { sh[0][tid] += sh[0][tid + off]; sh[1][tid] += sh[1][tid + off]; }
    __syncthreads();
  }
  if (tid == 0) {
    pstat[((size_t)b * 64 + c) * 2] = sh[0][0];
    pstat[((size_t)b * 64 + c) * 2 + 1] = sh[1][0];
  }
}

// ---------------- bn stats over v (f16): one (br,b,c) plane per block ----------------
__global__ __launch_bounds__(256) void bnv_partial_kernel(
    const _Float16* __restrict__ vb0, size_t vstrideH, float* __restrict__ pstat) {
  int c = blockIdx.x, b = blockIdx.y, br = blockIdx.z;
  int tid = threadIdx.x;
  const _Float16* row = vb0 + (size_t)br * vstrideH + ((size_t)b * 64 + c) * HW;
  float sm = 0.f, s2 = 0.f;
  #pragma unroll
  for (int i = 0; i < 2; i++) {
    H8 v; v.u4 = *(const uint4*)(row + (tid + i * 256) * 8);
    #pragma unroll
    for (int k = 0; k < 8; k++) { float t = (float)v.v[k]; sm += t; s2 += t * t; }
  }
  __shared__ float sh[2][256];
  sh[0][tid] = sm; sh[1][tid] = s2;
  __syncthreads();
  for (int off = 128; off > 0; off >>= 1) {
    if (tid < off) { sh[0][tid] += sh[0][tid + off]; sh[1][tid] += sh[1][tid + off]; }
    __syncthreads();
  }
  if (tid == 0) {
    pstat[(((size_t)br * 32 + b) * 64 + c) * 2] = sh[0][0];
    pstat[(((size_t)br * 32 + b) * 64 + c) * 2 + 1] = sh[1][0];
  }
}

// ---------------- pack static conv weights into MFMA A-fragment order ----------------
__global__ __launch_bounds__(256) void pack_static_kernel(
    const float* __restrict__ wk1c1, const float* __restrict__ wk1c2,
    const float* __restrict__ wk2c1, const float* __restrict__ wk2c2,
    const float* __restrict__ wconv, _Float16* __restrict__ wpk) {
  int idx = blockIdx.x * 256 + threadIdx.x;  // 258048
  int j = idx & 7, lane = (idx >> 3) & 63;
  int tap = (idx >> 9) % 9;
  int chunk = (idx / 4608) % 14;
  int br = idx / 64512;
  int g = lane >> 4;
  int c = (j < 4) ? 4 * g + j : 16 + 4 * g + (j - 4);
  const float* src; int ol0;
  if (chunk < 2)       { src = wk1c1 + (size_t)br * 32 * 288; ol0 = chunk * 16; }
  else if (chunk < 6)  { src = wk1c2 + (size_t)br * 64 * 288; ol0 = (chunk - 2) * 16; }
  else if (chunk < 8)  { src = wk2c1 + (size_t)br * 32 * 288; ol0 = (chunk - 6) * 16; }
  else if (chunk < 12) { src = wk2c2 + (size_t)br * 64 * 288; ol0 = (chunk - 8) * 16; }
  else                 { src = wconv + (size_t)br * 32 * 288; ol0 = (chunk - 12) * 16; }
  int o = ol0 + (lane & 15);
  wpk[idx] = (_Float16)(src[((size_t)o * 32 + c) * 9 + tap]);
}

// ---------------- MFMA conv: 9 shifted K=32 GEMMs; branch via blockIdx.z ----------------
// Pin the 36 h-fragments with 32-bit "+v" asm after the build: asm results cannot be
// rematerialized from LDS, forcing register residency across the chunk loop.
template <int MODE>
__global__ __launch_bounds__(256, 2) void conv_mfma_kernel(
    const float* __restrict__ xin, const _Float16* __restrict__ wAll,
    const float* __restrict__ pstat, const float* __restrict__ a_pre,
    int brBase, float* __restrict__ slabBase, size_t slabStride,
    _Float16* __restrict__ vb0, size_t vstrideH) {
  const int NCHUNK = (MODE == 0) ? 14 : 4;
  int bz = blockIdx.z;
  int br = brBase + bz;
  float* slab = slabBase + (size_t)bz * slabStride;
  __shared__ _Float16 hsh[6 * 66 * 36];  // [row6][col66][c-pad36]
  __shared__ float alsh[32], besh[32];
  int tid = threadIdx.x;
  int b = blockIdx.y, r0 = blockIdx.x * 4;
  int ch0 = (br & 1) * 32;
  if (MODE == 0 && tid < 32) {  // reduce x-stats + fold bn/shortcut into affine
    float s = 0.f, s2 = 0.f;
    for (int bb = 0; bb < 32; bb++) {
      size_t p = ((size_t)bb * 64 + ch0 + tid) * 2;
      s += pstat[p]; s2 += pstat[p + 1];
    }
    const float N = 131072.f;
    float m = s / N;
    float r = rsqrtf(s2 / N - m * m + EPSV);
    alsh[tid] = 0.5f * r + 0.01f * a_pre[br];
    besh[tid] = -0.5f * m * r;
  }
  __syncthreads();
  for (int t = tid; t < 384; t += 256) {  // zero halo cols
    int row = t >> 6, colh = ((t & 63) >> 5) ? 65 : 0, c = t & 31;
    hsh[(row * 66 + colh) * 36 + c] = (_Float16)0.f;
  }
  if (MODE == 0) {
    for (int t = tid; t < 32 * 96; t += 256) {  // float4 staging + affine
      int c = t / 96, p4 = (t % 96) * 4;
      int row = p4 >> 6, col = p4 & 63;
      int rg = r0 + row - 1;
      float4 v4 = {0.f, 0.f, 0.f, 0.f};
      if ((unsigned)rg < 64u)
        v4 = *(const float4*)&xin[((size_t)b * 64 + ch0 + c) * HW + (rg << 6) + col];
      float a = alsh[c], be = besh[c];
      _Float16* dst = &hsh[((size_t)row * 66 + col + 1) * 36 + c];
      dst[0]   = (_Float16)(v4.x * a + be);
      dst[36]  = (_Float16)(v4.y * a + be);
      dst[72]  = (_Float16)(v4.z * a + be);
      dst[108] = (_Float16)(v4.w * a + be);
    }
  } else {
    const _Float16* cin = (const _Float16*)(slab + OFF_CCB);
    for (int t = tid; t < 32 * 48; t += 256) {  // 16B staging
      int c = t / 48, p8 = (t % 48) * 8;
      int row = p8 >> 6, col = p8 & 63;
      int rg = r0 + row - 1;
      H8 v; v.u4 = make_uint4(0, 0, 0, 0);
      if ((unsigned)rg < 64u)
        v.u4 = *(const uint4*)&cin[((size_t)b * 32 + c) * HW + (rg << 6) + col];
      _Float16* dst = &hsh[((size_t)row * 66 + col + 1) * 36 + c];
      #pragma unroll
      for (int k = 0; k < 8; k++) dst[36 * k] = v.v[k];
    }
  }
  __syncthreads();
  int w = tid >> 6, l = tid & 63;
  int ln = l & 15, g = l >> 4;
  H8 bfr[4][9];
  #pragma unroll
  for (int pf = 0; pf < 4; pf++)
    #pragma unroll
    for (int dyi = 0; dyi < 3; dyi++)
      #pragma unroll
      for (int dxi = 0; dxi < 3; dxi++) {
        const _Float16* p = &hsh[(((size_t)(w + dyi)) * 66 + pf * 16 + ln + dxi) * 36 + 4 * g];
        H8 f;
        f.q[0] = *(const ushort4*)p;
        f.q[1] = *(const ushort4*)(p + 16);
        bfr[pf][dyi * 3 + dxi] = f;
      }
  // pin fragments in registers: asm outputs cannot be rematerialized from LDS
  // (32-bit tied operands — 128-bit tuples are unsupported by the backend)
  #pragma unroll
  for (int pf = 0; pf < 4; pf++)
    #pragma unroll
    for (int t = 0; t < 9; t++)
      asm volatile("" : "+v"(bfr[pf][t].u4.x), "+v"(bfr[pf][t].u4.y),
                        "+v"(bfr[pf][t].u4.z), "+v"(bfr[pf][t].u4.w));
  const _Float16* wb = (MODE == 0)
      ? wAll + (size_t)br * 64512
      : wAll + (size_t)br * 589824 + (size_t)b * 18432;
  for (int chunk = 0; chunk < NCHUNK; chunk++) {
    H8 af[9];
    #pragma unroll
    for (int t = 0; t < 9; t++)
      af[t].u4 = *(const uint4*)(wb + (((size_t)chunk * 9 + t) * 64 + l) * 8);
    _Float16* ob; int Cb, ol0;
    if (MODE == 0) {
      if (chunk < 2)       { ob = (_Float16*)(slab + OFF_Y1A); Cb = 32; ol0 = chunk * 16; }
      else if (chunk < 6)  { ob = (_Float16*)(slab + OFF_Y1B); Cb = 64; ol0 = (chunk - 2) * 16; }
      else if (chunk < 8)  { ob = (_Float16*)(slab + OFF_Y2A); Cb = 32; ol0 = (chunk - 6) * 16; }
      else if (chunk < 12) { ob = (_Float16*)(slab + OFF_Y2B); Cb = 64; ol0 = (chunk - 8) * 16; }
      else                 { ob = (_Float16*)(slab + OFF_CCB); Cb = 32; ol0 = (chunk - 12) * 16; }
    } else { ob = vb0 + (size_t)br * vstrideH; Cb = 64; ol0 = chunk * 16; }
    #pragma unroll
    for (int pf = 0; pf < 4; pf++) {
      f32x4 acc = {0.f, 0.f, 0.f, 0.f};
      #pragma unroll
      for (int t = 0; t < 9; t++)
        acc = __builtin_amdgcn_mfma_f32_16x16x32_f16(bfr[pf][t].v, af[t].v, acc, 0, 0, 0);
      union { _Float16 h[4]; ushort4 u; } sv;
      #pragma unroll
      for (int j = 0; j < 4; j++) sv.h[j] = (_Float16)acc[j];
      int px = ((r0 + w) << 6) + pf * 16 + 4 * g;
      *(ushort4*)&ob[((size_t)b * Cb + ol0 + ln) * HW + px] = sv.u;
    }
  }
}

// ---------------- attn1 MFMA: all 9 kk per block; 9 rows per block, dj-compacted LDS ----------------
// grid (7, 32, nslab); partials part1[rg][b][kk][o][i]  (P1 aliases dead y2a/y2b)
__global__ __launch_bounds__(256) void attn1_mfma_kernel(
    float* __restrict__ slabBase, size_t slabStride) {
  __shared__ _Float16 comp[3][96][34];  // [dj][ch 0-31=y1(i),32-95=y2(o)][q padded]
  int rg = blockIdx.x, b = blockIdx.y;
  float* slab = slabBase + (size_t)blockIdx.z * slabStride;
  const _Float16* y1 = (const _Float16*)(slab + OFF_Y1A);
  const _Float16* y2 = (const _Float16*)(slab + OFF_Y1B);
  int tid = threadIdx.x;
  for (int t = tid; t < 4896; t += 256) ((unsigned int*)comp)[t] = 0u;  // zero incl. q-pad
  int w = tid >> 6, lr = tid & 15, g = (tid >> 4) & 3;
  f32x4 acc[9][2];
  #pragma unroll
  for (int kk = 0; kk < 9; kk++) {
    acc[kk][0] = (f32x4){0.f, 0.f, 0.f, 0.f};
    acc[kk][1] = (f32x4){0.f, 0.f, 0.f, 0.f};
  }
  for (int tri = 0; tri < 3; tri++) {
    #pragma unroll
    for (int ri = 0; ri < 3; ri++) {  // di == ri (row base multiple of 3)
      int r = rg * 9 + tri * 3 + ri;
      __syncthreads();
      // stage row r, compacted by dj: each task = (ch, octet of 8 q's)
      for (int t = tid; t < 288; t += 256) {
        int ch = t / 3, oct = t % 3;
        const _Float16* src =
            (ch < 32 ? y1 + ((size_t)b * 32 + ch) * HW
                     : y2 + ((size_t)b * 64 + (ch - 32)) * HW) + (r << 6) + oct * 24;
        union { uint4 q[3]; ushort u[24]; } dat;
        dat.q[0] = *(const uint4*)(src);
        dat.q[1] = *(const uint4*)(src + 8);
        dat.q[2] = *(const uint4*)(src + 16);
        #pragma unroll
        for (int dj = 0; dj < 3; dj++) {
          union { ushort u[8]; uint4 q; } o_;
          #pragma unroll
          for (int m = 0; m < 8; m++) o_.u[m] = dat.u[dj + 3 * m];
          if (oct == 2) { o_.u[5] = 0; o_.u[6] = 0; o_.u[7] = 0; }  // q>20 invalid
          *(uint4*)&comp[dj][ch][oct * 8] = o_.q;
        }
      }
      __syncthreads();
      #pragma unroll
      for (int dj = 0; dj < 3; dj++) {
        H8 af, bf0, bf1;
        const _Float16* pa = &comp[dj][32 + 16 * w + lr][4 * g];
        af.q[0] = *(const ushort4*)pa;  af.q[1] = *(const ushort4*)(pa + 16);
        const _Float16* p0 = &comp[dj][lr][4 * g];
        bf0.q[0] = *(const ushort4*)p0; bf0.q[1] = *(const ushort4*)(p0 + 16);
        const _Float16* p1 = &comp[dj][16 + lr][4 * g];
        bf1.q[0] = *(const ushort4*)p1; bf1.q[1] = *(const ushort4*)(p1 + 16);
        acc[ri * 3 + dj][0] =
            __builtin_amdgcn_mfma_f32_16x16x32_f16(af.v, bf0.v, acc[ri * 3 + dj][0], 0, 0, 0);
        acc[ri * 3 + dj][1] =
            __builtin_amdgcn_mfma_f32_16x16x32_f16(af.v, bf1.v, acc[ri * 3 + dj][1], 0, 0, 0);
      }
    }
  }
  float* part = slab + OFF_P1;  // [rg][b][kk][o][i]
  #pragma unroll
  for (int kk = 0; kk < 9; kk++) {
    size_t base = (((size_t)rg * 32 + b) * 9 + kk) * 2048 + (16 * w + 4 * g) * 32 + lr;
    #pragma unroll
    for (int j = 0; j < 4; j++) {
      part[base + (size_t)j * 32] = acc[kk][0][j];
      part[base + (size_t)j * 32 + 16] = acc[kk][1][j];
    }
  }
}

// ---------------- attn2 MFMA: split-K over 8 pixel segments, vectorized staging ----------------
// grid (8, 32, nslab); partials part2[ps][b][o*32+i]   (runs BEFORE attn1)
__global__ __launch_bounds__(256) void attn2_mfma_kernel(
    float* __restrict__ slabBase, size_t slabStride) {
  __shared__ _Float16 comp[96][68];
  int ps = blockIdx.x, b = blockIdx.y;
  float* slab = slabBase + (size_t)blockIdx.z * slabStride;
  const _Float16* y1 = (const _Float16*)(slab + OFF_Y2A);
  const _Float16* y2 = (const _Float16*)(slab + OFF_Y2B);
  int tid = threadIdx.x;
  int w = tid >> 6, lr = tid & 15, g = (tid >> 4) & 3;
  f32x4 acc0 = {0.f, 0.f, 0.f, 0.f}, acc1 = {0.f, 0.f, 0.f, 0.f};
  for (int st = 0; st < 8; st++) {
    __syncthreads();
    #pragma unroll
    for (int t0 = 0; t0 < 3; t0++) {
      int t = tid + t0 * 256;  // 768 tasks: (ch, 8px part)
      int ch = t >> 3, part = t & 7;
      const _Float16* src =
          (ch < 32 ? y1 + ((size_t)b * 32 + ch) * HW
                   : y2 + ((size_t)b * 64 + (ch - 32)) * HW) + ps * 512 + st * 64 + part * 8;
      *(uint4*)&comp[ch][part * 8] = *(const uint4*)src;
    }
    __syncthreads();
    #pragma unroll
    for (int kh = 0; kh < 2; kh++) {
      H8 af, bf0, bf1;
      const _Float16* pa = &comp[32 + 16 * w + lr][kh * 32 + 4 * g];
      af.q[0] = *(const ushort4*)pa;  af.q[1] = *(const ushort4*)(pa + 16);
      const _Float16* p0 = &comp[lr][kh * 32 + 4 * g];
      bf0.q[0] = *(const ushort4*)p0; bf0.q[1] = *(const ushort4*)(p0 + 16);
      const _Float16* p1 = &comp[16 + lr][kh * 32 + 4 * g];
      bf1.q[0] = *(const ushort4*)p1; bf1.q[1] = *(const ushort4*)(p1 + 16);
      acc0 = __builtin_amdgcn_mfma_f32_16x16x32_f16(af.v, bf0.v, acc0, 0, 0, 0);
      acc1 = __builtin_amdgcn_mfma_f32_16x16x32_f16(af.v, bf1.v, acc1, 0, 0, 0);
    }
  }
  float* p2 = slab + OFF_P2;
  size_t base = ((size_t)ps * 32 + b) * 2048 + (16 * w + 4 * g) * 32 + lr;
  #pragma unroll
  for (int j = 0; j < 4; j++) {
    p2[base + (size_t)j * 32] = acc0[j];
    p2[base + (size_t)j * 32 + 16] = acc1[j];
  }
}

// ---------------- fused: reduce partials + softmax + ak + pack ----------------
__global__ __launch_bounds__(320) void fused_ak_kernel(
    float* __restrict__ slabBase, size_t slabStride, int brBase,
    const float* __restrict__ aw, _Float16* __restrict__ wdynB) {
  int o = blockIdx.x, b = blockIdx.y;
  int bz = blockIdx.z, br = brBase + bz;
  float* slab = slabBase + (size_t)bz * slabStride;
  const float* part1 = slab + OFF_P1;
  const float* part2 = slab + OFF_P2;
  const float* awb = aw + (size_t)br * 18432;
  _Float16* wdyn = wdynB + (size_t)br * 589824;
  int tid = threadIdx.x;
  __shared__ float sm[33];
  if (tid < 32) {
    float s = 0.f;
    #pragma unroll
    for (int ps = 0; ps < 8; ps++) s += part2[((size_t)ps * 32 + b) * 2048 + o * 32 + tid];
    sm[tid] = s * 0.17677669529663687f;  // 1/sqrt(32)
  }
  __syncthreads();
  if (tid == 0) {
    float mx = -1e30f;
    for (int k = 0; k < 32; k++) mx = fmaxf(mx, sm[k]);
    float sum = 0.f;
    for (int k = 0; k < 32; k++) { float e = expf(sm[k] - mx); sm[k] = e; sum += e; }
    sm[32] = 1.0f / sum;
  }
  __syncthreads();
  if (tid < 288) {
    int i = tid / 9, kk = tid % 9;
    float a1v = 0.f;
    #pragma unroll
    for (int rg = 0; rg < 7; rg++)
      a1v += part1[(((size_t)rg * 32 + b) * 9 + kk) * 2048 + o * 32 + i];
    a1v *= 0.05892556509887896f;  // 1/sqrt(288)
    float akv = sm[i] * sm[32] * (a1v + awb[(size_t)(o * 32 + i) * 9 + kk]);
    int chunk = o >> 4;
    int g = (i & 15) >> 2;
    int j = (i & 3) + ((i >= 16) ? 4 : 0);
    int lane = (g << 4) | (o & 15);
    wdyn[((((size_t)b * 4 + chunk) * 9 + kk) * 64 + lane) * 8 + j] = (_Float16)akv;
  }
}

// ---------------- fused finalize: v-stats reduce + 4-branch combine ----------------
__global__ __launch_bounds__(256) void finalize_kernel(
    const _Float16* __restrict__ vb0, size_t vstrideH,
    const float* __restrict__ pstat, const float* __restrict__ a_post,
    const float* __restrict__ x, const float* __restrict__ cm,
    float* __restrict__ out) {
  __shared__ float sga[256], sgb[256];
  int t = threadIdx.x;
  {
    int br = t >> 6, o = t & 63;
    float s = 0.f, s2 = 0.f;
    for (int bb = 0; bb < 32; bb++) {
      size_t p = (((size_t)br * 32 + bb) * 64 + o) * 2;
      s += pstat[p]; s2 += pstat[p + 1];
    }
    const float N = 131072.f;
    float m = s / N;
    float r = rsqrtf(s2 / N - m * m + EPSV);
    sga[t] = 0.5f * r + 0.6f * a_post[br];
    sgb[t] = -0.5f * m * r;
  }
  __syncthreads();
  size_t g8 = ((size_t)blockIdx.x * 256 + threadIdx.x) * 8;
  int o = (int)((g8 >> 12) & 63);
  float acc[8], ysv[8];
  #pragma unroll
  for (int br = 0; br < 4; br++) {
    float ga = sga[br * 64 + o], gb = sgb[br * 64 + o];
    H8 v; v.u4 = *(const uint4*)(vb0 + (size_t)br * vstrideH + g8);
    #pragma unroll
    for (int j = 0; j < 8; j++) {
      float y = ga * (float)v.v[j] + gb;
      if (br == 0) acc[j] = y;
      else if (br == 1) acc[j] += y;
      else if (br == 2) ysv[j] = y;
      else acc[j] += ysv[j] * y;
    }
  }
  float cmv = 0.99f * cm[0];
  const float4* xp = (const float4*)(x + g8);
  float4 x0 = xp[0], x1 = xp[1];
  float4 o0, o1;
  o0.x = cmv * x0.x + acc[0] * 0.5773502691896258f;
  o0.y = cmv * x0.y + acc[1] * 0.5773502691896258f;
  o0.z = cmv * x0.z + acc[2] * 0.5773502691896258f;
  o0.w = cmv * x0.w + acc[3] * 0.5773502691896258f;
  o1.x = cmv * x1.x + acc[4] * 0.5773502691896258f;
  o1.y = cmv * x1.y + acc[5] * 0.5773502691896258f;
  o1.z = cmv * x1.z + acc[6] * 0.5773502691896258f;
  o1.w = cmv * x1.w + acc[7] * 0.5773502691896258f;
  float4* op = (float4*)(out + g8);
  op[0] = o0;
  op[1] = o1;
}

extern "C" void kernel_launch(void* const* d_in, const int* in_sizes, int n_in,
                              void* d_out, int out_size, void* d_ws, size_t ws_size,
                              hipStream_t stream) {
  const float* x      = (const float*)d_in[0];
  const float* wk1c1  = (const float*)d_in[1];
  const float* wk1c2  = (const float*)d_in[2];
  const float* wk2c1  = (const float*)d_in[3];
  const float* wk2c2  = (const float*)d_in[4];
  const float* wconv  = (const float*)d_in[5];
  const float* attn_w = (const float*)d_in[6];
  const float* a_pre  = (const float*)d_in[7];
  const float* a_post = (const float*)d_in[8];
  const float* cm     = (const float*)d_in[9];
  float* out = (float*)d_out;

  const size_t FIX_F  = 129024ull + 1179648ull + 16384ull;  // wpk + wdyn + pstat
  const size_t VBUF_F = 16777216ull;                        // fallback-only dedicated vbuf
  size_t wsF = ws_size / 4;
  int nslab;
  if (wsF >= 4 * SLAB_F + FIX_F) nslab = 4;
  else if (wsF >= 2 * SLAB_F + FIX_F + VBUF_F) nslab = 2;
  else nslab = 1;

  float* ws = (float*)d_ws;
  float* slab0 = ws;
  float* fixF  = ws + (size_t)nslab * SLAB_F;
  _Float16* wpk   = (_Float16*)fixF;
  _Float16* wdynB = (_Float16*)(fixF + 129024);
  float* pstat    = fixF + 129024 + 1179648;
  // vbuf: 4-slab path aliases each slab's dead y1a region; fallback uses dedicated region
  _Float16* vb0;
  size_t VSH;
  if (nslab == 4) { vb0 = (_Float16*)(slab0 + OFF_Y1A); VSH = SLAB_F * 2; }
  else            { vb0 = (_Float16*)(fixF + FIX_F);    VSH = 8388608ull; }

  bn_partial_kernel<<<dim3(64, 32), 256, 0, stream>>>(x, pstat);
  pack_static_kernel<<<1008, 256, 0, stream>>>(wk1c1, wk1c2, wk2c1, wk2c2, wconv, wpk);

  for (int b0 = 0; b0 < 4; b0 += nslab) {
    conv_mfma_kernel<0><<<dim3(16, 32, nslab), 256, 0, stream>>>(
        x, wpk, pstat, a_pre, b0, slab0, SLAB_F, nullptr, 0);
    // attn2 first: frees y2a/y2b so attn1's P1 (aliasing them) is safe
    attn2_mfma_kernel<<<dim3(8, 32, nslab), 256, 0, stream>>>(slab0, SLAB_F);
    attn1_mfma_kernel<<<dim3(7, 32, nslab), 256, 0, stream>>>(slab0, SLAB_F);
    fused_ak_kernel<<<dim3(64, 32, nslab), 320, 0, stream>>>(
        slab0, SLAB_F, b0, attn_w, wdynB);
    conv_mfma_kernel<1><<<dim3(16, 32, nslab), 256, 0, stream>>>(
        nullptr, wdynB, nullptr, nullptr, b0, slab0, SLAB_F, vb0, VSH);
  }

  bnv_partial_kernel<<<dim3(64, 32, 4), 256, 0, stream>>>(vb0, VSH, pstat);
  finalize_kernel<<<4096, 256, 0, stream>>>(vb0, VSH, pstat, a_post, x, cm, out);
}

// Round 21
// 354.850 us; speedup vs baseline: 1.0622x; 1.0345x over previous
//
#include <hip/hip_runtime.h>
#include <math.h>

#define HW 4096
#define EPSV 1e-5f

typedef _Float16 half8 __attribute__((ext_vector_type(8)));
typedef float f32x4 __attribute__((ext_vector_type(4)));
union H8 { half8 v; ushort4 q[2]; uint4 u4; };

// slab layout (float offsets) — lifetime-aliased, 15,204,352 floats/slab
#define SLAB_F  15204352ull
#define OFF_Y1A 0
#define OFF_Y1B 2097152
#define OFF_Y2A 6291456
#define OFF_Y2B 8388608
#define OFF_CCB 12582912
#define OFF_P2  14680064
#define OFF_P1  6291456

// ---------------- bn stats over x: one (b,c) plane per block, float4 ----------------
__global__ __launch_bounds__(256) void bn_partial_kernel(
    const float* __restrict__ x, float* __restrict__ pstat) {
  int c = blockIdx.x, b = blockIdx.y;
  int tid = threadIdx.x;
  const float4* p = (const float4*)(x + ((size_t)b * 64 + c) * HW);
  float sm = 0.f, s2 = 0.f;
  #pragma unroll
  for (int i = 0; i < 4; i++) {
    float4 v = p[tid + i * 256];
    sm += v.x + v.y + v.z + v.w;
    s2 += v.x * v.x + v.y * v.y + v.z * v.z + v.w * v.w;
  }
  __shared__ float sh[2][256];
  sh[0][tid] = sm; sh[1][tid] = s2;
  __syncthreads();
  for (int off = 128; off > 0; off >>= 1) {
    if (tid < off) { sh[0][tid] += sh[0][tid + off]; sh[1][tid] += sh[1][tid + off]; }
    __syncthreads();
  }
  if (tid == 0) {
    pstat[((size_t)b * 64 + c) * 2] = sh[0][0];
    pstat[((size_t)b * 64 + c) * 2 + 1] = sh[1][0];
  }
}

// ---------------- pack static conv weights into MFMA A-fragment order ----------------
// also zeroes the 512-float v-stats accumulator (graph-safe per-call reset)
__global__ __launch_bounds__(256) void pack_static_kernel(
    const float* __restrict__ wk1c1, const float* __restrict__ wk1c2,
    const float* __restrict__ wk2c1, const float* __restrict__ wk2c2,
    const float* __restrict__ wconv, _Float16* __restrict__ wpk,
    float* __restrict__ vstat) {
  int idx = blockIdx.x * 256 + threadIdx.x;  // 258048
  if (idx < 512) vstat[idx] = 0.f;
  int j = idx & 7, lane = (idx >> 3) & 63;
  int tap = (idx >> 9) % 9;
  int chunk = (idx / 4608) % 14;
  int br = idx / 64512;
  int g = lane >> 4;
  int c = (j < 4) ? 4 * g + j : 16 + 4 * g + (j - 4);
  const float* src; int ol0;
  if (chunk < 2)       { src = wk1c1 + (size_t)br * 32 * 288; ol0 = chunk * 16; }
  else if (chunk < 6)  { src = wk1c2 + (size_t)br * 64 * 288; ol0 = (chunk - 2) * 16; }
  else if (chunk < 8)  { src = wk2c1 + (size_t)br * 32 * 288; ol0 = (chunk - 6) * 16; }
  else if (chunk < 12) { src = wk2c2 + (size_t)br * 64 * 288; ol0 = (chunk - 8) * 16; }
  else                 { src = wconv + (size_t)br * 32 * 288; ol0 = (chunk - 12) * 16; }
  int o = ol0 + (lane & 15);
  wpk[idx] = (_Float16)(src[((size_t)o * 32 + c) * 9 + tap]);
}

// ---------------- MFMA conv: 9 shifted K=32 GEMMs; branch via blockIdx.z ----------------
// MODE1 additionally accumulates v-stats (sum, sum^2 of the fp16-rounded outputs)
// via shfl-reduce + LDS atomics + one global atomicAdd per (ch,stat) per block.
template <int MODE>
__global__ __launch_bounds__(256) void conv_mfma_kernel(
    const float* __restrict__ xin, const _Float16* __restrict__ wAll,
    const float* __restrict__ pstat, const float* __restrict__ a_pre,
    int brBase, float* __restrict__ slabBase, size_t slabStride,
    _Float16* __restrict__ vb0, size_t vstrideH, float* __restrict__ vstat) {
  const int NCHUNK = (MODE == 0) ? 14 : 4;
  int bz = blockIdx.z;
  int br = brBase + bz;
  float* slab = slabBase + (size_t)bz * slabStride;
  __shared__ _Float16 hsh[6 * 66 * 36];  // [row6][col66][c-pad36]
  __shared__ float alsh[32], besh[32];
  __shared__ float sredS[(MODE == 1) ? 128 : 1];
  int tid = threadIdx.x;
  int b = blockIdx.y, r0 = blockIdx.x * 4;
  int ch0 = (br & 1) * 32;
  if (MODE == 0 && tid < 32) {  // reduce x-stats + fold bn/shortcut into affine
    float s = 0.f, s2 = 0.f;
    for (int bb = 0; bb < 32; bb++) {
      size_t p = ((size_t)bb * 64 + ch0 + tid) * 2;
      s += pstat[p]; s2 += pstat[p + 1];
    }
    const float N = 131072.f;
    float m = s / N;
    float r = rsqrtf(s2 / N - m * m + EPSV);
    alsh[tid] = 0.5f * r + 0.01f * a_pre[br];
    besh[tid] = -0.5f * m * r;
  }
  __syncthreads();
  for (int t = tid; t < 384; t += 256) {  // zero halo cols
    int row = t >> 6, colh = ((t & 63) >> 5) ? 65 : 0, c = t & 31;
    hsh[(row * 66 + colh) * 36 + c] = (_Float16)0.f;
  }
  if (MODE == 0) {
    for (int t = tid; t < 32 * 96; t += 256) {  // float4 staging + affine
      int c = t / 96, p4 = (t % 96) * 4;
      int row = p4 >> 6, col = p4 & 63;
      int rg = r0 + row - 1;
      float4 v4 = {0.f, 0.f, 0.f, 0.f};
      if ((unsigned)rg < 64u)
        v4 = *(const float4*)&xin[((size_t)b * 64 + ch0 + c) * HW + (rg << 6) + col];
      float a = alsh[c], be = besh[c];
      _Float16* dst = &hsh[((size_t)row * 66 + col + 1) * 36 + c];
      dst[0]   = (_Float16)(v4.x * a + be);
      dst[36]  = (_Float16)(v4.y * a + be);
      dst[72]  = (_Float16)(v4.z * a + be);
      dst[108] = (_Float16)(v4.w * a + be);
    }
  } else {
    if (tid < 128) sredS[tid] = 0.f;
    const _Float16* cin = (const _Float16*)(slab + OFF_CCB);
    for (int t = tid; t < 32 * 48; t += 256) {  // 16B staging
      int c = t / 48, p8 = (t % 48) * 8;
      int row = p8 >> 6, col = p8 & 63;
      int rg = r0 + row - 1;
      H8 v; v.u4 = make_uint4(0, 0, 0, 0);
      if ((unsigned)rg < 64u)
        v.u4 = *(const uint4*)&cin[((size_t)b * 32 + c) * HW + (rg << 6) + col];
      _Float16* dst = &hsh[((size_t)row * 66 + col + 1) * 36 + c];
      #pragma unroll
      for (int k = 0; k < 8; k++) dst[36 * k] = v.v[k];
    }
  }
  __syncthreads();
  int w = tid >> 6, l = tid & 63;
  int ln = l & 15, g = l >> 4;
  H8 bfr[4][9];
  #pragma unroll
  for (int pf = 0; pf < 4; pf++)
    #pragma unroll
    for (int dyi = 0; dyi < 3; dyi++)
      #pragma unroll
      for (int dxi = 0; dxi < 3; dxi++) {
        const _Float16* p = &hsh[(((size_t)(w + dyi)) * 66 + pf * 16 + ln + dxi) * 36 + 4 * g];
        H8 f;
        f.q[0] = *(const ushort4*)p;
        f.q[1] = *(const ushort4*)(p + 16);
        bfr[pf][dyi * 3 + dxi] = f;
      }
  const _Float16* wb = (MODE == 0)
      ? wAll + (size_t)br * 64512
      : wAll + (size_t)br * 589824 + (size_t)b * 18432;
  for (int chunk = 0; chunk < NCHUNK; chunk++) {
    H8 af[9];
    #pragma unroll
    for (int t = 0; t < 9; t++)
      af[t].u4 = *(const uint4*)(wb + (((size_t)chunk * 9 + t) * 64 + l) * 8);
    _Float16* ob; int Cb, ol0;
    if (MODE == 0) {
      if (chunk < 2)       { ob = (_Float16*)(slab + OFF_Y1A); Cb = 32; ol0 = chunk * 16; }
      else if (chunk < 6)  { ob = (_Float16*)(slab + OFF_Y1B); Cb = 64; ol0 = (chunk - 2) * 16; }
      else if (chunk < 8)  { ob = (_Float16*)(slab + OFF_Y2A); Cb = 32; ol0 = (chunk - 6) * 16; }
      else if (chunk < 12) { ob = (_Float16*)(slab + OFF_Y2B); Cb = 64; ol0 = (chunk - 8) * 16; }
      else                 { ob = (_Float16*)(slab + OFF_CCB); Cb = 32; ol0 = (chunk - 12) * 16; }
    } else { ob = vb0 + (size_t)br * vstrideH; Cb = 64; ol0 = chunk * 16; }
    float ls = 0.f, ls2 = 0.f;
    #pragma unroll
    for (int pf = 0; pf < 4; pf++) {
      f32x4 acc = {0.f, 0.f, 0.f, 0.f};
      #pragma unroll
      for (int t = 0; t < 9; t++)
        acc = __builtin_amdgcn_mfma_f32_16x16x32_f16(bfr[pf][t].v, af[t].v, acc, 0, 0, 0);
      union { _Float16 h[4]; ushort4 u; } sv;
      #pragma unroll
      for (int j = 0; j < 4; j++) sv.h[j] = (_Float16)acc[j];
      int px = ((r0 + w) << 6) + pf * 16 + 4 * g;
      *(ushort4*)&ob[((size_t)b * Cb + ol0 + ln) * HW + px] = sv.u;
      if (MODE == 1) {
        #pragma unroll
        for (int j = 0; j < 4; j++) { float t = (float)sv.h[j]; ls += t; ls2 += t * t; }
      }
    }
    if (MODE == 1) {
      // reduce over g-groups (lane bits 4,5): all 4 lanes {ln, ln+16, ln+32, ln+48}
      ls  += __shfl_xor(ls, 16, 64);
      ls  += __shfl_xor(ls, 32, 64);
      ls2 += __shfl_xor(ls2, 16, 64);
      ls2 += __shfl_xor(ls2, 32, 64);
      if (l < 16) {
        atomicAdd(&sredS[(chunk * 16 + ln) * 2], ls);
        atomicAdd(&sredS[(chunk * 16 + ln) * 2 + 1], ls2);
      }
    }
  }
  if (MODE == 1) {
    __syncthreads();
    if (tid < 128) atomicAdd(&vstat[(size_t)br * 128 + tid], sredS[tid]);
  }
}

// ---------------- attn1 MFMA: all 9 kk per block; 9 rows per block, dj-compacted LDS ----------------
// grid (7, 32, nslab); partials part1[rg][b][kk][o][i]  (P1 aliases dead y2a/y2b)
__global__ __launch_bounds__(256) void attn1_mfma_kernel(
    float* __restrict__ slabBase, size_t slabStride) {
  __shared__ _Float16 comp[3][96][34];  // [dj][ch 0-31=y1(i),32-95=y2(o)][q padded]
  int rg = blockIdx.x, b = blockIdx.y;
  float* slab = slabBase + (size_t)blockIdx.z * slabStride;
  const _Float16* y1 = (const _Float16*)(slab + OFF_Y1A);
  const _Float16* y2 = (const _Float16*)(slab + OFF_Y1B);
  int tid = threadIdx.x;
  for (int t = tid; t < 4896; t += 256) ((unsigned int*)comp)[t] = 0u;  // zero incl. q-pad
  int w = tid >> 6, lr = tid & 15, g = (tid >> 4) & 3;
  f32x4 acc[9][2];
  #pragma unroll
  for (int kk = 0; kk < 9; kk++) {
    acc[kk][0] = (f32x4){0.f, 0.f, 0.f, 0.f};
    acc[kk][1] = (f32x4){0.f, 0.f, 0.f, 0.f};
  }
  for (int tri = 0; tri < 3; tri++) {
    #pragma unroll
    for (int ri = 0; ri < 3; ri++) {  // di == ri (row base multiple of 3)
      int r = rg * 9 + tri * 3 + ri;
      __syncthreads();
      // stage row r, compacted by dj: each task = (ch, octet of 8 q's)
      for (int t = tid; t < 288; t += 256) {
        int ch = t / 3, oct = t % 3;
        const _Float16* src =
            (ch < 32 ? y1 + ((size_t)b * 32 + ch) * HW
                     : y2 + ((size_t)b * 64 + (ch - 32)) * HW) + (r << 6) + oct * 24;
        union { uint4 q[3]; ushort u[24]; } dat;
        dat.q[0] = *(const uint4*)(src);
        dat.q[1] = *(const uint4*)(src + 8);
        dat.q[2] = *(const uint4*)(src + 16);
        #pragma unroll
        for (int dj = 0; dj < 3; dj++) {
          union { ushort u[8]; uint4 q; } o_;
          #pragma unroll
          for (int m = 0; m < 8; m++) o_.u[m] = dat.u[dj + 3 * m];
          if (oct == 2) { o_.u[5] = 0; o_.u[6] = 0; o_.u[7] = 0; }  // q>20 invalid
          *(uint4*)&comp[dj][ch][oct * 8] = o_.q;
        }
      }
      __syncthreads();
      #pragma unroll
      for (int dj = 0; dj < 3; dj++) {
        H8 af, bf0, bf1;
        const _Float16* pa = &comp[dj][32 + 16 * w + lr][4 * g];
        af.q[0] = *(const ushort4*)pa;  af.q[1] = *(const ushort4*)(pa + 16);
        const _Float16* p0 = &comp[dj][lr][4 * g];
        bf0.q[0] = *(const ushort4*)p0; bf0.q[1] = *(const ushort4*)(p0 + 16);
        const _Float16* p1 = &comp[dj][16 + lr][4 * g];
        bf1.q[0] = *(const ushort4*)p1; bf1.q[1] = *(const ushort4*)(p1 + 16);
        acc[ri * 3 + dj][0] =
            __builtin_amdgcn_mfma_f32_16x16x32_f16(af.v, bf0.v, acc[ri * 3 + dj][0], 0, 0, 0);
        acc[ri * 3 + dj][1] =
            __builtin_amdgcn_mfma_f32_16x16x32_f16(af.v, bf1.v, acc[ri * 3 + dj][1], 0, 0, 0);
      }
    }
  }
  float* part = slab + OFF_P1;  // [rg][b][kk][o][i]
  #pragma unroll
  for (int kk = 0; kk < 9; kk++) {
    size_t base = (((size_t)rg * 32 + b) * 9 + kk) * 2048 + (16 * w + 4 * g) * 32 + lr;
    #pragma unroll
    for (int j = 0; j < 4; j++) {
      part[base + (size_t)j * 32] = acc[kk][0][j];
      part[base + (size_t)j * 32 + 16] = acc[kk][1][j];
    }
  }
}

// ---------------- attn2 MFMA: split-K over 8 pixel segments, vectorized staging ----------------
// grid (8, 32, nslab); partials part2[ps][b][o*32+i]   (runs BEFORE attn1)
__global__ __launch_bounds__(256) void attn2_mfma_kernel(
    float* __restrict__ slabBase, size_t slabStride) {
  __shared__ _Float16 comp[96][68];
  int ps = blockIdx.x, b = blockIdx.y;
  float* slab = slabBase + (size_t)blockIdx.z * slabStride;
  const _Float16* y1 = (const _Float16*)(slab + OFF_Y2A);
  const _Float16* y2 = (const _Float16*)(slab + OFF_Y2B);
  int tid = threadIdx.x;
  int w = tid >> 6, lr = tid & 15, g = (tid >> 4) & 3;
  f32x4 acc0 = {0.f, 0.f, 0.f, 0.f}, acc1 = {0.f, 0.f, 0.f, 0.f};
  for (int st = 0; st < 8; st++) {
    __syncthreads();
    #pragma unroll
    for (int t0 = 0; t0 < 3; t0++) {
      int t = tid + t0 * 256;  // 768 tasks: (ch, 8px part)
      int ch = t >> 3, part = t & 7;
      const _Float16* src =
          (ch < 32 ? y1 + ((size_t)b * 32 + ch) * HW
                   : y2 + ((size_t)b * 64 + (ch - 32)) * HW) + ps * 512 + st * 64 + part * 8;
      *(uint4*)&comp[ch][part * 8] = *(const uint4*)src;
    }
    __syncthreads();
    #pragma unroll
    for (int kh = 0; kh < 2; kh++) {
      H8 af, bf0, bf1;
      const _Float16* pa = &comp[32 + 16 * w + lr][kh * 32 + 4 * g];
      af.q[0] = *(const ushort4*)pa;  af.q[1] = *(const ushort4*)(pa + 16);
      const _Float16* p0 = &comp[lr][kh * 32 + 4 * g];
      bf0.q[0] = *(const ushort4*)p0; bf0.q[1] = *(const ushort4*)(p0 + 16);
      const _Float16* p1 = &comp[16 + lr][kh * 32 + 4 * g];
      bf1.q[0] = *(const ushort4*)p1; bf1.q[1] = *(const ushort4*)(p1 + 16);
      acc0 = __builtin_amdgcn_mfma_f32_16x16x32_f16(af.v, bf0.v, acc0, 0, 0, 0);
      acc1 = __builtin_amdgcn_mfma_f32_16x16x32_f16(af.v, bf1.v, acc1, 0, 0, 0);
    }
  }
  float* p2 = slab + OFF_P2;
  size_t base = ((size_t)ps * 32 + b) * 2048 + (16 * w + 4 * g) * 32 + lr;
  #pragma unroll
  for (int j = 0; j < 4; j++) {
    p2[base + (size_t)j * 32] = acc0[j];
    p2[base + (size_t)j * 32 + 16] = acc1[j];
  }
}

// ---------------- fused: reduce partials + softmax + ak + pack ----------------
__global__ __launch_bounds__(320) void fused_ak_kernel(
    float* __restrict__ slabBase, size_t slabStride, int brBase,
    const float* __restrict__ aw, _Float16* __restrict__ wdynB) {
  int o = blockIdx.x, b = blockIdx.y;
  int bz = blockIdx.z, br = brBase + bz;
  float* slab = slabBase + (size_t)bz * slabStride;
  const float* part1 = slab + OFF_P1;
  const float* part2 = slab + OFF_P2;
  const float* awb = aw + (size_t)br * 18432;
  _Float16* wdyn = wdynB + (size_t)br * 589824;
  int tid = threadIdx.x;
  __shared__ float sm[33];
  if (tid < 32) {
    float s = 0.f;
    #pragma unroll
    for (int ps = 0; ps < 8; ps++) s += part2[((size_t)ps * 32 + b) * 2048 + o * 32 + tid];
    sm[tid] = s * 0.17677669529663687f;  // 1/sqrt(32)
  }
  __syncthreads();
  if (tid == 0) {
    float mx = -1e30f;
    for (int k = 0; k < 32; k++) mx = fmaxf(mx, sm[k]);
    float sum = 0.f;
    for (int k = 0; k < 32; k++) { float e = expf(sm[k] - mx); sm[k] = e; sum += e; }
    sm[32] = 1.0f / sum;
  }
  __syncthreads();
  if (tid < 288) {
    int i = tid / 9, kk = tid % 9;
    float a1v = 0.f;
    #pragma unroll
    for (int rg = 0; rg < 7; rg++)
      a1v += part1[(((size_t)rg * 32 + b) * 9 + kk) * 2048 + o * 32 + i];
    a1v *= 0.05892556509887896f;  // 1/sqrt(288)
    float akv = sm[i] * sm[32] * (a1v + awb[(size_t)(o * 32 + i) * 9 + kk]);
    int chunk = o >> 4;
    int g = (i & 15) >> 2;
    int j = (i & 3) + ((i >= 16) ? 4 : 0);
    int lane = (g << 4) | (o & 15);
    wdyn[((((size_t)b * 4 + chunk) * 9 + kk) * 64 + lane) * 8 + j] = (_Float16)akv;
  }
}

// ---------------- fused finalize: direct v-stats + 4-branch combine ----------------
__global__ __launch_bounds__(256) void finalize_kernel(
    const _Float16* __restrict__ vb0, size_t vstrideH,
    const float* __restrict__ vstat, const float* __restrict__ a_post,
    const float* __restrict__ x, const float* __restrict__ cm,
    float* __restrict__ out) {
  __shared__ float sga[256], sgb[256];
  int t = threadIdx.x;
  {
    int br = t >> 6, o = t & 63;
    float s  = vstat[(size_t)br * 128 + o * 2];
    float s2 = vstat[(size_t)br * 128 + o * 2 + 1];
    const float N = 131072.f;
    float m = s / N;
    float r = rsqrtf(s2 / N - m * m + EPSV);
    sga[t] = 0.5f * r + 0.6f * a_post[br];
    sgb[t] = -0.5f * m * r;
  }
  __syncthreads();
  size_t g8 = ((size_t)blockIdx.x * 256 + threadIdx.x) * 8;
  int o = (int)((g8 >> 12) & 63);
  float acc[8], ysv[8];
  #pragma unroll
  for (int br = 0; br < 4; br++) {
    float ga = sga[br * 64 + o], gb = sgb[br * 64 + o];
    H8 v; v.u4 = *(const uint4*)(vb0 + (size_t)br * vstrideH + g8);
    #pragma unroll
    for (int j = 0; j < 8; j++) {
      float y = ga * (float)v.v[j] + gb;
      if (br == 0) acc[j] = y;
      else if (br == 1) acc[j] += y;
      else if (br == 2) ysv[j] = y;
      else acc[j] += ysv[j] * y;
    }
  }
  float cmv = 0.99f * cm[0];
  const float4* xp = (const float4*)(x + g8);
  float4 x0 = xp[0], x1 = xp[1];
  float4 o0, o1;
  o0.x = cmv * x0.x + acc[0] * 0.5773502691896258f;
  o0.y = cmv * x0.y + acc[1] * 0.5773502691896258f;
  o0.z = cmv * x0.z + acc[2] * 0.5773502691896258f;
  o0.w = cmv * x0.w + acc[3] * 0.5773502691896258f;
  o1.x = cmv * x1.x + acc[4] * 0.5773502691896258f;
  o1.y = cmv * x1.y + acc[5] * 0.5773502691896258f;
  o1.z = cmv * x1.z + acc[6] * 0.5773502691896258f;
  o1.w = cmv * x1.w + acc[7] * 0.5773502691896258f;
  float4* op = (float4*)(out + g8);
  op[0] = o0;
  op[1] = o1;
}

extern "C" void kernel_launch(void* const* d_in, const int* in_sizes, int n_in,
                              void* d_out, int out_size, void* d_ws, size_t ws_size,
                              hipStream_t stream) {
  const float* x      = (const float*)d_in[0];
  const float* wk1c1  = (const float*)d_in[1];
  const float* wk1c2  = (const float*)d_in[2];
  const float* wk2c1  = (const float*)d_in[3];
  const float* wk2c2  = (const float*)d_in[4];
  const float* wconv  = (const float*)d_in[5];
  const float* attn_w = (const float*)d_in[6];
  const float* a_pre  = (const float*)d_in[7];
  const float* a_post = (const float*)d_in[8];
  const float* cm     = (const float*)d_in[9];
  float* out = (float*)d_out;

  const size_t FIX_F  = 129024ull + 1179648ull + 16384ull;  // wpk + wdyn + pstat(+vstat)
  const size_t VBUF_F = 16777216ull;                        // fallback-only dedicated vbuf
  size_t wsF = ws_size / 4;
  int nslab;
  if (wsF >= 4 * SLAB_F + FIX_F) nslab = 4;
  else if (wsF >= 2 * SLAB_F + FIX_F + VBUF_F) nslab = 2;
  else nslab = 1;

  float* ws = (float*)d_ws;
  float* slab0 = ws;
  float* fixF  = ws + (size_t)nslab * SLAB_F;
  _Float16* wpk   = (_Float16*)fixF;
  _Float16* wdynB = (_Float16*)(fixF + 129024);
  float* pstat    = fixF + 129024 + 1179648;
  float* vstat    = pstat + 4096;  // 512 floats
  // vbuf: 4-slab path aliases each slab's dead y1a region; fallback uses dedicated region
  _Float16* vb0;
  size_t VSH;
  if (nslab == 4) { vb0 = (_Float16*)(slab0 + OFF_Y1A); VSH = SLAB_F * 2; }
  else            { vb0 = (_Float16*)(fixF + FIX_F);    VSH = 8388608ull; }

  bn_partial_kernel<<<dim3(64, 32), 256, 0, stream>>>(x, pstat);
  pack_static_kernel<<<1008, 256, 0, stream>>>(wk1c1, wk1c2, wk2c1, wk2c2, wconv, wpk, vstat);

  for (int b0 = 0; b0 < 4; b0 += nslab) {
    conv_mfma_kernel<0><<<dim3(16, 32, nslab), 256, 0, stream>>>(
        x, wpk, pstat, a_pre, b0, slab0, SLAB_F, nullptr, 0, nullptr);
    // attn2 first: frees y2a/y2b so attn1's P1 (aliasing them) is safe
    attn2_mfma_kernel<<<dim3(8, 32, nslab), 256, 0, stream>>>(slab0, SLAB_F);
    attn1_mfma_kernel<<<dim3(7, 32, nslab), 256, 0, stream>>>(slab0, SLAB_F);
    fused_ak_kernel<<<dim3(64, 32, nslab), 320, 0, stream>>>(
        slab0, SLAB_F, b0, attn_w, wdynB);
    conv_mfma_kernel<1><<<dim3(16, 32, nslab), 256, 0, stream>>>(
        nullptr, wdynB, nullptr, nullptr, b0, slab0, SLAB_F, vb0, VSH, vstat);
  }

  finalize_kernel<<<4096, 256, 0, stream>>>(vb0, VSH, vstat, a_post, x, cm, out);
}